// Round 8
// baseline (384.077 us; speedup 1.0000x reference)
//
#include <hip/hip_runtime.h>
#include <cmath>

#define DW 300
#define HH 128
#define G3 384
#define GN 768
#define SS 256
#define NB 128
#define NC 10
#define DC 16
#define NCDC 160
#define CAP_EPS 1e-7f
#define KP 320

typedef _Float16 h8v __attribute__((ext_vector_type(8)));
typedef _Float16 h4v __attribute__((ext_vector_type(4)));
typedef float f32x4 __attribute__((ext_vector_type(4)));

__device__ __forceinline__ float rcp_(float x) { return __builtin_amdgcn_rcpf(x); }
__device__ __forceinline__ float sigmoidf_(float x) {
  return rcp_(1.0f + __expf(-x));
}
__device__ __forceinline__ float tanhf_(float x) {
  return 1.0f - 2.0f * rcp_(__expf(2.0f * x) + 1.0f);
}
// LDS-only barrier: don't drain vmcnt, so global loads/stores stay in flight.
// sched_barrier(0) pins the scheduler so nothing migrates across the fence.
__device__ __forceinline__ void bar_lds() {
  asm volatile("s_waitcnt lgkmcnt(0)\n\ts_barrier" ::: "memory");
  __builtin_amdgcn_sched_barrier(0);
}

// ---------------------------------------------------------------------------
// K0: gather emb rows -> A16[32768][320] fp16 (K padded 300->320 with zeros),
// convert w_ih (f+b) -> Bw16[768][320], transpose W_cap -> WcT[160][256].
// ---------------------------------------------------------------------------
__global__ __launch_bounds__(64) void k0_prep(
    const int* __restrict__ x, const float* __restrict__ emb,
    const float* __restrict__ wif, const float* __restrict__ wib,
    const float* __restrict__ Wc,
    _Float16* __restrict__ A16, _Float16* __restrict__ Bw16,
    _Float16* __restrict__ WcT)
{
  const int row = blockIdx.x;
  const int t = threadIdx.x;
  if (row < 33536) {
    const float* __restrict__ src;
    _Float16* __restrict__ dst;
    if (row < 32768) {
      src = emb + (size_t)x[(row & 127) * SS + (row >> 7)] * DW;
      dst = A16 + (size_t)row * KP;
    } else {
      const int n = row - 32768;
      src = (n < G3) ? (wif + (size_t)n * DW) : (wib + (size_t)(n - G3) * DW);
      dst = Bw16 + (size_t)n * KP;
    }
#pragma unroll
    for (int p = 0; p < 2; ++p) {
      const int idx = p * 64 + t;
      if (idx < 75) {
        const float4 v = *(const float4*)(src + idx * 4);
        h4v o = {(_Float16)v.x, (_Float16)v.y, (_Float16)v.z, (_Float16)v.w};
        *(h4v*)(dst + idx * 4) = o;
      }
    }
    if (t < 5) {
      h4v z = {(_Float16)0.f, (_Float16)0.f, (_Float16)0.f, (_Float16)0.f};
      *(h4v*)(dst + 300 + t * 4) = z;
    }
  } else {
    const int n = row - 33536;   // 0..159
    _Float16* __restrict__ dst = WcT + (size_t)n * 256;
#pragma unroll
    for (int p = 0; p < 4; ++p) {
      const int k = p * 64 + t;
      dst[k] = (_Float16)Wc[(size_t)k * NCDC + n];
    }
  }
}

// ---------------------------------------------------------------------------
// K1: fp16 MFMA GEMM for x-projection.
// m-tile (128) == one timestep s, all 128 batches; n-tile (128) == one (dir,G).
// Epilogue: bias add + fp16 repack via LDS, store to
// xp16[dir][b][s][G*128+j]  (contiguous 768B per (seq,step) for k2).
// ---------------------------------------------------------------------------
__global__ __launch_bounds__(256) void k1_xproj(
    const _Float16* __restrict__ A16, const _Float16* __restrict__ Bw16,
    const float* __restrict__ bf, const float* __restrict__ bb,
    _Float16* __restrict__ xp16)
{
  __shared__ __align__(16) _Float16 Asb[128 * 64];
  __shared__ __align__(16) _Float16 Bsb[128 * 64];
  __shared__ __align__(16) _Float16 Ls[128 * 132];   // repack, padded stride
  const int tid = threadIdx.x;
  const int s_idx = blockIdx.x;          // timestep
  const int n0 = blockIdx.y * 128;       // (dir, G)
  const int m0 = s_idx * 128;
  const int dir = (n0 >= G3) ? 1 : 0;
  const int G = (n0 >> 7) - dir * 3;

  const int lane = tid & 63;
  const int wv = tid >> 6, wm = wv >> 1, wn = wv & 1;
  const int fr = lane & 15, kc4 = lane >> 4;

  const int srow = tid >> 3;   // 0..31 (+i*32)
  const int sch  = tid & 7;    // 16B chunk within 128B row

  f32x4 acc[4][4];
#pragma unroll
  for (int i = 0; i < 4; ++i)
#pragma unroll
    for (int j = 0; j < 4; ++j) acc[i][j] = (f32x4){0.f, 0.f, 0.f, 0.f};

  h8v ra[4], rb[4];
#pragma unroll
  for (int i = 0; i < 4; ++i) {
    const int r = i * 32 + srow;
    ra[i] = *(const h8v*)(A16 + (size_t)(m0 + r) * KP + sch * 8);
    rb[i] = *(const h8v*)(Bw16 + (size_t)(n0 + r) * KP + sch * 8);
  }

  for (int kt = 0; kt < 5; ++kt) {
    if (kt) bar_lds();                    // prev frag reads done
#pragma unroll
    for (int i = 0; i < 4; ++i) {
      const int r = i * 32 + srow;
      const int off = (r * 128 + sch * 16) ^ ((r & 7) << 4);
      *(h8v*)((char*)Asb + off) = ra[i];
      *(h8v*)((char*)Bsb + off) = rb[i];
    }
    if (kt < 4) {
      const int kb = (kt + 1) * 64;
#pragma unroll
      for (int i = 0; i < 4; ++i) {
        const int r = i * 32 + srow;
        ra[i] = *(const h8v*)(A16 + (size_t)(m0 + r) * KP + kb + sch * 8);
        rb[i] = *(const h8v*)(Bw16 + (size_t)(n0 + r) * KP + kb + sch * 8);
      }
    }
    bar_lds();                            // staged tile visible

    h8v af[4][2], bfv[4][2];
#pragma unroll
    for (int mf = 0; mf < 4; ++mf) {
      const int rA = wm * 64 + mf * 16 + fr;
#pragma unroll
      for (int ks = 0; ks < 2; ++ks) {
        const int off = (rA * 128 + ks * 64 + kc4 * 16) ^ ((rA & 7) << 4);
        af[mf][ks] = *(const h8v*)((const char*)Asb + off);
      }
    }
#pragma unroll
    for (int nf = 0; nf < 4; ++nf) {
      const int rB = wn * 64 + nf * 16 + fr;
#pragma unroll
      for (int ks = 0; ks < 2; ++ks) {
        const int off = (rB * 128 + ks * 64 + kc4 * 16) ^ ((rB & 7) << 4);
        bfv[nf][ks] = *(const h8v*)((const char*)Bsb + off);
      }
    }
#pragma unroll
    for (int ks = 0; ks < 2; ++ks)
#pragma unroll
      for (int mf = 0; mf < 4; ++mf)
#pragma unroll
        for (int nf = 0; nf < 4; ++nf)
          acc[mf][nf] = __builtin_amdgcn_mfma_f32_16x16x32_f16(
              af[mf][ks], bfv[nf][ks], acc[mf][nf], 0, 0, 0);
  }

  // ---- epilogue: bias + fp16 repack in LDS, then coalesced store ----
  const float* __restrict__ bsrc = (n0 < G3) ? (bf + n0) : (bb + (n0 - G3));
  float bval[4];
#pragma unroll
  for (int nf = 0; nf < 4; ++nf) bval[nf] = bsrc[wn * 64 + nf * 16 + fr];

#pragma unroll
  for (int mf = 0; mf < 4; ++mf)
#pragma unroll
    for (int e = 0; e < 4; ++e) {
      const int r = wm * 64 + mf * 16 + kc4 * 4 + e;   // batch b
#pragma unroll
      for (int nf = 0; nf < 4; ++nf) {
        const int c = wn * 64 + nf * 16 + fr;          // j within gate
        Ls[r * 132 + c] = (_Float16)(acc[mf][nf][e] + bval[nf]);
      }
    }
  __syncthreads();

  // 256 threads: unit = (row b, half): 128B contiguous per unit
  {
    const int r = tid >> 1;
    const int hf = tid & 1;
    _Float16* __restrict__ dst =
        xp16 + ((size_t)(dir * NB + r) * SS + s_idx) * G3 + G * 128 + hf * 64;
    const _Float16* srcl = &Ls[r * 132 + hf * 64];
#pragma unroll
    for (int i = 0; i < 8; ++i)
      *(h8v*)(dst + i * 8) = *(const h8v*)(srcl + i * 8);
  }
}

// ---------------------------------------------------------------------------
// K2: GRU recurrence via MFMA, 4 sequences per block.
// Grid 64 = 2 dirs x 32 batch-groups; 4 waves; wave wv owns j-tiles {2wv,2wv+1}.
// A = w_hh fragments (persistent VGPRs, j_local = lane&15 rows);
// B = h for 4 batches (LDS, 16 rows x 272B padded stride -> ~2-way banks);
// D[j_local][batch]: lanes fr<4 each handle 8 gate units (2jt x 4e).
// PROVEN two-barrier protocol: read-all -> bar -> gates+write -> bar.
// ---------------------------------------------------------------------------
__global__ __launch_bounds__(256, 1) void k2_gru(
    const _Float16* __restrict__ xp16,
    const float* __restrict__ whf, const float* __restrict__ whb,
    const float* __restrict__ bhf, const float* __restrict__ bhb,
    _Float16* __restrict__ hcat16)
{
  const int blk = blockIdx.x;      // 0..63
  const int dir = blk >> 5;        // 0 fwd / 1 bwd
  const int bg  = blk & 31;        // batch group of 4
  const int tid = threadIdx.x;
  const int wv  = tid >> 6;        // 0..3
  const int lane = tid & 63;
  const int fr = lane & 15;        // B-col: batch (0..3 active)
  const int qq = lane >> 4;        // k-group / D row-group
  const bool act = (fr < 4);

  const float* __restrict__ wh = dir ? whb : whf;
  const float* __restrict__ bh = dir ? bhb : bhf;

  // A fragments (w_hh rows, j_local = fr) + bias vectors, persistent
  h8v wA[2][3][4];
  f32x4 bias4[2][3];
#pragma unroll
  for (int jt = 0; jt < 2; ++jt) {
    const int jg = 2 * wv + jt;
#pragma unroll
    for (int G = 0; G < 3; ++G) {
      const int row = G * HH + jg * 16 + fr;
      const float* __restrict__ p = wh + (size_t)row * HH;
#pragma unroll
      for (int kc = 0; kc < 4; ++kc) {
        const float* q = p + kc * 32 + qq * 8;
        const float4 u0 = *(const float4*)(q);
        const float4 u1 = *(const float4*)(q + 4);
        wA[jt][G][kc] = (h8v){(_Float16)u0.x, (_Float16)u0.y, (_Float16)u0.z,
                              (_Float16)u0.w, (_Float16)u1.x, (_Float16)u1.y,
                              (_Float16)u1.z, (_Float16)u1.w};
      }
      bias4[jt][G] = *(const f32x4*)(bh + G * HH + jg * 16 + qq * 4);
    }
  }

  // h in LDS: [16 rows][136 halfs] (272B stride -> rows offset by 4 words)
  __shared__ __align__(16) _Float16 h16[16 * 136];
  for (int i = tid; i < 16 * 136; i += 256) h16[i] = (_Float16)0.f;
  __syncthreads();

  const int stp = dir ? -1 : 1;
  int s = dir ? (SS - 1) : 0;
  const ptrdiff_t xstp = (ptrdiff_t)stp * G3;
  const ptrdiff_t hstp = (ptrdiff_t)stp * 256;
  const int bmine = bg * 4 + (act ? fr : 0);
  const _Float16* __restrict__ xptr =
      xp16 + (size_t)(dir * NB + bmine) * SS * G3 + (size_t)s * G3;
  _Float16* __restrict__ hptr =
      hcat16 + ((size_t)bmine * SS + s) * 256 + dir * HH;

  h4v xv[2][3] = {};
  if (act) {
#pragma unroll
    for (int jt = 0; jt < 2; ++jt)
#pragma unroll
      for (int G = 0; G < 3; ++G)
        xv[jt][G] = *(const h4v*)(xptr + G * 128 + (2 * wv + jt) * 16 + qq * 4);
  }

  f32x4 hold[2] = {{0.f, 0.f, 0.f, 0.f}, {0.f, 0.f, 0.f, 0.f}};

  for (int it = 0; it < SS; ++it) {
    // B fragments: h columns (batch = fr), k = kc*32 + qq*8 + e
    h8v hB[4];
#pragma unroll
    for (int kc = 0; kc < 4; ++kc)
      hB[kc] = *(const h8v*)(&h16[fr * 136 + kc * 32 + qq * 8]);

    h4v xc[2][3];
#pragma unroll
    for (int jt = 0; jt < 2; ++jt)
#pragma unroll
      for (int G = 0; G < 3; ++G) xc[jt][G] = xv[jt][G];
    if (it < SS - 1) {
      xptr += xstp;
      if (act) {
#pragma unroll
        for (int jt = 0; jt < 2; ++jt)
#pragma unroll
          for (int G = 0; G < 3; ++G)
            xv[jt][G] =
                *(const h4v*)(xptr + G * 128 + (2 * wv + jt) * 16 + qq * 4);
      }
    }

    f32x4 acc[2][3];
#pragma unroll
    for (int jt = 0; jt < 2; ++jt) {
#pragma unroll
      for (int G = 0; G < 3; ++G) {
        acc[jt][G] = bias4[jt][G];
        if (G < 2) {
#pragma unroll
          for (int e = 0; e < 4; ++e) acc[jt][G][e] += (float)xc[jt][G][e];
        }
      }
#pragma unroll
      for (int G = 0; G < 3; ++G)
#pragma unroll
        for (int kc = 0; kc < 4; ++kc)
          acc[jt][G] = __builtin_amdgcn_mfma_f32_16x16x32_f16(
              wA[jt][G][kc], hB[kc], acc[jt][G], 0, 0, 0);
    }

    bar_lds();   // all waves' h reads complete before overwrite

    if (act) {
#pragma unroll
      for (int jt = 0; jt < 2; ++jt) {
        f32x4 hn;
#pragma unroll
        for (int e = 0; e < 4; ++e) {
          const float r = sigmoidf_(acc[jt][0][e]);
          const float z = sigmoidf_(acc[jt][1][e]);
          const float n = tanhf_((float)xc[jt][2][e] + r * acc[jt][2][e]);
          hn[e] = (1.f - z) * n + z * hold[jt][e];
        }
        hold[jt] = hn;
        const h4v hv = {(_Float16)hn[0], (_Float16)hn[1],
                        (_Float16)hn[2], (_Float16)hn[3]};
        const int j0 = (2 * wv + jt) * 16 + qq * 4;
        *(h4v*)(&h16[fr * 136 + j0]) = hv;
        *(h4v*)(hptr + j0) = hv;
      }
    }
    hptr += hstp;
    bar_lds();   // h_new visible for next step
  }
}

// ---------------------------------------------------------------------------
// K3: uh[m][n] = sum_k hcat16[m][k] * Wc[k][n]  (fp16 MFMA)
// 128-M tile x full N=160, K=256 staged whole in 64KB swizzled LDS.
// ---------------------------------------------------------------------------
__global__ __launch_bounds__(256) void k3_uhat(
    const _Float16* __restrict__ hcat16, const _Float16* __restrict__ WcT,
    float* __restrict__ uh)
{
  __shared__ __align__(16) _Float16 Hs[128 * 256];   // 64KB
  const int tid = threadIdx.x;
  const int m0 = blockIdx.x * 128;
  const int lane = tid & 63, wv = tid >> 6;
  const int fr = lane & 15, qq = lane >> 4;

  const int srow = tid >> 5;   // 0..7
  const int sch  = tid & 31;   // 16B chunk of 512B row
#pragma unroll
  for (int i = 0; i < 16; ++i) {
    const int r = i * 8 + srow;
    const h8v v = *(const h8v*)(hcat16 + (size_t)(m0 + r) * 256 + sch * 8);
    const int off = (r * 512 + sch * 16) ^ ((r & 7) << 4);
    *(h8v*)((char*)Hs + off) = v;
  }
  __syncthreads();

  f32x4 acc[2][10];
#pragma unroll
  for (int mt = 0; mt < 2; ++mt)
#pragma unroll
    for (int nt = 0; nt < 10; ++nt) acc[mt][nt] = (f32x4){0.f, 0.f, 0.f, 0.f};

#pragma unroll
  for (int kc = 0; kc < 8; ++kc) {
    h8v bf_[10];
#pragma unroll
    for (int nt = 0; nt < 10; ++nt)
      bf_[nt] = *(const h8v*)(WcT + (size_t)(nt * 16 + fr) * 256 + kc * 32 + qq * 8);
    h8v af[2];
#pragma unroll
    for (int mt = 0; mt < 2; ++mt) {
      const int rA = wv * 32 + mt * 16 + fr;
      const int off = (rA * 512 + kc * 64 + qq * 16) ^ ((rA & 7) << 4);
      af[mt] = *(const h8v*)((const char*)Hs + off);
    }
#pragma unroll
    for (int mt = 0; mt < 2; ++mt)
#pragma unroll
      for (int nt = 0; nt < 10; ++nt)
        acc[mt][nt] = __builtin_amdgcn_mfma_f32_16x16x32_f16(
            af[mt], bf_[nt], acc[mt][nt], 0, 0, 0);
  }

#pragma unroll
  for (int mt = 0; mt < 2; ++mt)
#pragma unroll
    for (int nt = 0; nt < 10; ++nt)
#pragma unroll
      for (int e = 0; e < 4; ++e) {
        const int m = m0 + wv * 32 + mt * 16 + qq * 4 + e;
        uh[(size_t)m * NCDC + nt * 16 + fr] = acc[mt][nt][e];
      }
}

// ---------------------------------------------------------------------------
// K4: dynamic routing + final linear. One block per batch element.
// ---------------------------------------------------------------------------
__global__ __launch_bounds__(256) void k4_route(
    const float* __restrict__ uhat, const float* __restrict__ Wl,
    const float* __restrict__ bl, float* __restrict__ outp)
{
  const int b = blockIdx.x;
  const int t = threadIdx.x;
  __shared__ float blog[NC][SS + 1];
  __shared__ float cbuf[NC][SS + 1];
  __shared__ float vout[NC][DC];
  __shared__ float red0[256], red1[256];

  const float* __restrict__ u = uhat + (size_t)b * SS * NCDC;

#pragma unroll
  for (int i = 0; i < NC; ++i) blog[i][t] = 0.f;
  __syncthreads();

  const int ci = t >> 4, ck = t & 15;
  float myval = 0.f;

  for (int it = 0; it < 5; ++it) {
    float m = blog[0][t];
#pragma unroll
    for (int i = 1; i < NC; ++i) m = fmaxf(m, blog[i][t]);
    float e[NC];
    float sum = 0.f;
#pragma unroll
    for (int i = 0; i < NC; ++i) { e[i] = __expf(blog[i][t] - m); sum += e[i]; }
    const float inv = __builtin_amdgcn_rcpf(sum);
#pragma unroll
    for (int i = 0; i < NC; ++i) cbuf[i][t] = e[i] * inv;
    __syncthreads();

    if (t < NCDC) {
      float acc = 0.f;
#pragma unroll 4
      for (int jj = 0; jj < SS; ++jj)
        acc += cbuf[ci][jj] * u[(size_t)jj * NCDC + t];
      float ss = acc * acc;
      ss += __shfl_xor(ss, 1);
      ss += __shfl_xor(ss, 2);
      ss += __shfl_xor(ss, 4);
      ss += __shfl_xor(ss, 8);
      myval = acc * __builtin_amdgcn_rsqf(ss + CAP_EPS);
      vout[ci][ck] = myval;
    }
    __syncthreads();

    if (it < 4) {
      const float* ur = u + (size_t)t * NCDC;
#pragma unroll
      for (int i = 0; i < NC; ++i) {
        float dot = 0.f;
#pragma unroll
        for (int k = 0; k < DC; ++k) dot += ur[i * DC + k] * vout[i][k];
        blog[i][t] += dot;
      }
      __syncthreads();
    }
  }

  float p0 = 0.f, p1 = 0.f;
  if (t < NCDC) { p0 = myval * Wl[2 * t]; p1 = myval * Wl[2 * t + 1]; }
  red0[t] = p0; red1[t] = p1;
  __syncthreads();
  for (int off = 128; off >= 1; off >>= 1) {
    if (t < off) { red0[t] += red0[t + off]; red1[t] += red1[t + off]; }
    __syncthreads();
  }
  if (t == 0) {
    outp[2 * b + 0] = red0[0] + bl[0];
    outp[2 * b + 1] = red1[0] + bl[1];
  }
}

extern "C" void kernel_launch(void* const* d_in, const int* in_sizes, int n_in,
                              void* d_out, int out_size, void* d_ws, size_t ws_size,
                              hipStream_t stream) {
  (void)in_sizes; (void)n_in; (void)out_size; (void)ws_size;
  const int*   x    = (const int*)  d_in[0];
  const float* emb  = (const float*)d_in[1];
  const float* wif  = (const float*)d_in[2];
  const float* whf  = (const float*)d_in[3];
  const float* bif  = (const float*)d_in[4];
  const float* bhf  = (const float*)d_in[5];
  const float* wib  = (const float*)d_in[6];
  const float* whb  = (const float*)d_in[7];
  const float* bib  = (const float*)d_in[8];
  const float* bhb  = (const float*)d_in[9];
  const float* Wc   = (const float*)d_in[10];
  const float* Wl   = (const float*)d_in[11];
  const float* bl   = (const float*)d_in[12];
  float* out = (float*)d_out;

  char* base = (char*)d_ws;
  _Float16* xp16   = (_Float16*)base;                       //  50.33 MB
  _Float16* hcat16 = (_Float16*)(base + 50331648);          //  16.78 MB
  float*    uh     = (float*)   (base + 67108864);          //  20.97 MB
  _Float16* A16    = (_Float16*)(base + 88080384);          //  20.97 MB
  _Float16* Bw16   = (_Float16*)(base + 109051904);         //   0.49 MB
  _Float16* WcT    = (_Float16*)(base + 109543424);         //   0.08 MB

  hipLaunchKernelGGL(k0_prep, dim3(33696), dim3(64), 0, stream,
                     x, emb, wif, wib, Wc, A16, Bw16, WcT);
  hipLaunchKernelGGL(k1_xproj, dim3(256, 6), dim3(256), 0, stream,
                     A16, Bw16, bif, bib, xp16);
  hipLaunchKernelGGL(k2_gru, dim3(64), dim3(256), 0, stream,
                     xp16, whf, whb, bhf, bhb, hcat16);
  hipLaunchKernelGGL(k3_uhat, dim3(256), dim3(256), 0, stream,
                     hcat16, WcT, uh);
  hipLaunchKernelGGL(k4_route, dim3(128), dim3(256), 0, stream,
                     uh, Wl, bl, out);
}

// Round 9
// 314.513 us; speedup vs baseline: 1.2212x; 1.2212x over previous
//
#include <hip/hip_runtime.h>
#include <cmath>

#define DW 300
#define HH 128
#define G3 384
#define GN 768
#define SS 256
#define NB 128
#define NC 10
#define DC 16
#define NCDC 160
#define CAP_EPS 1e-7f
#define KP 320

typedef _Float16 h8v __attribute__((ext_vector_type(8)));
typedef _Float16 h4v __attribute__((ext_vector_type(4)));
typedef float f32x4 __attribute__((ext_vector_type(4)));

__device__ __forceinline__ float rcp_(float x) { return __builtin_amdgcn_rcpf(x); }
__device__ __forceinline__ float sigmoidf_(float x) {
  return rcp_(1.0f + __expf(-x));
}
__device__ __forceinline__ float tanhf_(float x) {
  return 1.0f - 2.0f * rcp_(__expf(2.0f * x) + 1.0f);
}
// LDS-only barrier: don't drain vmcnt, so global loads/stores stay in flight.
// NOTE: no sched_barrier(0) — R7's pinning collapsed VALUBusy 43->21%.
__device__ __forceinline__ void bar_lds() {
  asm volatile("s_waitcnt lgkmcnt(0)\n\ts_barrier" ::: "memory");
}

// ---------------------------------------------------------------------------
// K0: gather emb rows -> A16[32768][320] fp16 (K padded 300->320 with zeros),
// convert w_ih (f+b) -> Bw16[768][320], transpose W_cap -> WcT[160][256].
// ---------------------------------------------------------------------------
__global__ __launch_bounds__(64) void k0_prep(
    const int* __restrict__ x, const float* __restrict__ emb,
    const float* __restrict__ wif, const float* __restrict__ wib,
    const float* __restrict__ Wc,
    _Float16* __restrict__ A16, _Float16* __restrict__ Bw16,
    _Float16* __restrict__ WcT)
{
  const int row = blockIdx.x;
  const int t = threadIdx.x;
  if (row < 33536) {
    const float* __restrict__ src;
    _Float16* __restrict__ dst;
    if (row < 32768) {
      src = emb + (size_t)x[(row & 127) * SS + (row >> 7)] * DW;
      dst = A16 + (size_t)row * KP;
    } else {
      const int n = row - 32768;
      src = (n < G3) ? (wif + (size_t)n * DW) : (wib + (size_t)(n - G3) * DW);
      dst = Bw16 + (size_t)n * KP;
    }
#pragma unroll
    for (int p = 0; p < 2; ++p) {
      const int idx = p * 64 + t;
      if (idx < 75) {
        const float4 v = *(const float4*)(src + idx * 4);
        h4v o = {(_Float16)v.x, (_Float16)v.y, (_Float16)v.z, (_Float16)v.w};
        *(h4v*)(dst + idx * 4) = o;
      }
    }
    if (t < 5) {
      h4v z = {(_Float16)0.f, (_Float16)0.f, (_Float16)0.f, (_Float16)0.f};
      *(h4v*)(dst + 300 + t * 4) = z;
    }
  } else {
    const int n = row - 33536;   // 0..159
    _Float16* __restrict__ dst = WcT + (size_t)n * 256;
#pragma unroll
    for (int p = 0; p < 4; ++p) {
      const int k = p * 64 + t;
      dst[k] = (_Float16)Wc[(size_t)k * NCDC + n];
    }
  }
}

// ---------------------------------------------------------------------------
// K1: fp16 MFMA GEMM for x-projection.
// m-tile (128) == one timestep s, all 128 batches; n-tile (128) == one (dir,G).
// Epilogue: bias add + fp16 repack via LDS, store to
// xp16[dir][b][s][G*128+j]  (contiguous 768B per (seq,step) for k2).
// ---------------------------------------------------------------------------
__global__ __launch_bounds__(256) void k1_xproj(
    const _Float16* __restrict__ A16, const _Float16* __restrict__ Bw16,
    const float* __restrict__ bf, const float* __restrict__ bb,
    _Float16* __restrict__ xp16)
{
  __shared__ __align__(16) _Float16 Asb[128 * 64];
  __shared__ __align__(16) _Float16 Bsb[128 * 64];
  __shared__ __align__(16) _Float16 Ls[128 * 132];   // repack, padded stride
  const int tid = threadIdx.x;
  const int s_idx = blockIdx.x;          // timestep
  const int n0 = blockIdx.y * 128;       // (dir, G)
  const int m0 = s_idx * 128;
  const int dir = (n0 >= G3) ? 1 : 0;
  const int G = (n0 >> 7) - dir * 3;

  const int lane = tid & 63;
  const int wv = tid >> 6, wm = wv >> 1, wn = wv & 1;
  const int fr = lane & 15, kc4 = lane >> 4;

  const int srow = tid >> 3;   // 0..31 (+i*32)
  const int sch  = tid & 7;    // 16B chunk within 128B row

  f32x4 acc[4][4];
#pragma unroll
  for (int i = 0; i < 4; ++i)
#pragma unroll
    for (int j = 0; j < 4; ++j) acc[i][j] = (f32x4){0.f, 0.f, 0.f, 0.f};

  h8v ra[4], rb[4];
#pragma unroll
  for (int i = 0; i < 4; ++i) {
    const int r = i * 32 + srow;
    ra[i] = *(const h8v*)(A16 + (size_t)(m0 + r) * KP + sch * 8);
    rb[i] = *(const h8v*)(Bw16 + (size_t)(n0 + r) * KP + sch * 8);
  }

  for (int kt = 0; kt < 5; ++kt) {
    if (kt) bar_lds();                    // prev frag reads done
#pragma unroll
    for (int i = 0; i < 4; ++i) {
      const int r = i * 32 + srow;
      const int off = (r * 128 + sch * 16) ^ ((r & 7) << 4);
      *(h8v*)((char*)Asb + off) = ra[i];
      *(h8v*)((char*)Bsb + off) = rb[i];
    }
    if (kt < 4) {
      const int kb = (kt + 1) * 64;
#pragma unroll
      for (int i = 0; i < 4; ++i) {
        const int r = i * 32 + srow;
        ra[i] = *(const h8v*)(A16 + (size_t)(m0 + r) * KP + kb + sch * 8);
        rb[i] = *(const h8v*)(Bw16 + (size_t)(n0 + r) * KP + kb + sch * 8);
      }
    }
    bar_lds();                            // staged tile visible

    h8v af[4][2], bfv[4][2];
#pragma unroll
    for (int mf = 0; mf < 4; ++mf) {
      const int rA = wm * 64 + mf * 16 + fr;
#pragma unroll
      for (int ks = 0; ks < 2; ++ks) {
        const int off = (rA * 128 + ks * 64 + kc4 * 16) ^ ((rA & 7) << 4);
        af[mf][ks] = *(const h8v*)((const char*)Asb + off);
      }
    }
#pragma unroll
    for (int nf = 0; nf < 4; ++nf) {
      const int rB = wn * 64 + nf * 16 + fr;
#pragma unroll
      for (int ks = 0; ks < 2; ++ks) {
        const int off = (rB * 128 + ks * 64 + kc4 * 16) ^ ((rB & 7) << 4);
        bfv[nf][ks] = *(const h8v*)((const char*)Bsb + off);
      }
    }
#pragma unroll
    for (int ks = 0; ks < 2; ++ks)
#pragma unroll
      for (int mf = 0; mf < 4; ++mf)
#pragma unroll
        for (int nf = 0; nf < 4; ++nf)
          acc[mf][nf] = __builtin_amdgcn_mfma_f32_16x16x32_f16(
              af[mf][ks], bfv[nf][ks], acc[mf][nf], 0, 0, 0);
  }

  // ---- epilogue: bias + fp16 repack in LDS, then coalesced store ----
  const float* __restrict__ bsrc = (n0 < G3) ? (bf + n0) : (bb + (n0 - G3));
  float bval[4];
#pragma unroll
  for (int nf = 0; nf < 4; ++nf) bval[nf] = bsrc[wn * 64 + nf * 16 + fr];

#pragma unroll
  for (int mf = 0; mf < 4; ++mf)
#pragma unroll
    for (int e = 0; e < 4; ++e) {
      const int r = wm * 64 + mf * 16 + kc4 * 4 + e;   // batch b
#pragma unroll
      for (int nf = 0; nf < 4; ++nf) {
        const int c = wn * 64 + nf * 16 + fr;          // j within gate
        Ls[r * 132 + c] = (_Float16)(acc[mf][nf][e] + bval[nf]);
      }
    }
  __syncthreads();

  // 256 threads: unit = (row b, half): 128B contiguous per unit
  {
    const int r = tid >> 1;
    const int hf = tid & 1;
    _Float16* __restrict__ dst =
        xp16 + ((size_t)(dir * NB + r) * SS + s_idx) * G3 + G * 128 + hf * 64;
    const _Float16* srcl = &Ls[r * 132 + hf * 64];
#pragma unroll
    for (int i = 0; i < 8; ++i)
      *(h8v*)(dst + i * 8) = *(const h8v*)(srcl + i * 8);
  }
}

// ---------------------------------------------------------------------------
// K2: GRU recurrence via MFMA, both directions fused per block.
// 128 blocks x 8 waves (512 thr): waves 0-3 = fwd, 4-7 = bwd -> 2 waves/SIMD.
// Wave handles 2 j-tiles x 3 gates; w_hh^T fragments persistent in VGPRs.
// PROVEN two-barrier protocol: read-all -> bar -> gate-write -> bar.
// rcp-based activations; pointer-bump addressing. NO sched_barrier pinning.
// ---------------------------------------------------------------------------
__global__ __launch_bounds__(512, 2) void k2_gru(
    const _Float16* __restrict__ xp16,
    const float* __restrict__ whf, const float* __restrict__ whb,
    const float* __restrict__ bhf, const float* __restrict__ bhb,
    _Float16* __restrict__ hcat16)
{
  const int b = blockIdx.x;        // 0..127
  const int tid = threadIdx.x;
  const int wave = tid >> 6;       // 0..7
  const int dir = wave >> 2;       // 0 fwd / 1 bwd
  const int wv = wave & 3;         // j-tile pair owner
  const int lane = tid & 63;
  const int fr = lane & 15;
  const int qq = lane >> 4;

  const float* __restrict__ wh = dir ? whb : whf;
  const float* __restrict__ bh = dir ? bhb : bhf;

  // B fragments (w_hh^T) + biases, persistent in VGPRs
  h8v wB[2][3][4];
  float bias_[2][3];
#pragma unroll
  for (int jt = 0; jt < 2; ++jt) {
    const int jg = 2 * wv + jt;
#pragma unroll
    for (int G = 0; G < 3; ++G) {
      const int row = G * HH + jg * 16 + fr;
      const float* __restrict__ p = wh + (size_t)row * HH;
#pragma unroll
      for (int kc = 0; kc < 4; ++kc) {
        const float* q = p + kc * 32 + qq * 8;
        const float4 u0 = *(const float4*)(q);
        const float4 u1 = *(const float4*)(q + 4);
        wB[jt][G][kc] = (h8v){(_Float16)u0.x, (_Float16)u0.y, (_Float16)u0.z,
                              (_Float16)u0.w, (_Float16)u1.x, (_Float16)u1.y,
                              (_Float16)u1.z, (_Float16)u1.w};
      }
      bias_[jt][G] = bh[G * HH + jg * 16 + fr];
    }
  }

  __shared__ __align__(16) _Float16 h16[2][HH];   // [dir][j], 512 B
  if (tid < 32) *(f32x4*)((char*)h16 + tid * 16) = (f32x4){0.f, 0.f, 0.f, 0.f};
  __syncthreads();

  const int stp = dir ? -1 : 1;
  int s = dir ? (SS - 1) : 0;
  const ptrdiff_t xstp = (ptrdiff_t)stp * G3;
  const ptrdiff_t hstp = (ptrdiff_t)stp * 256;
  const _Float16* __restrict__ xptr =
      xp16 + (size_t)(dir * NB + b) * SS * G3 + (size_t)s * G3;
  _Float16* __restrict__ hptr =
      hcat16 + ((size_t)b * SS + s) * 256 + dir * HH;

  _Float16 xv[2][3];
#pragma unroll
  for (int jt = 0; jt < 2; ++jt)
#pragma unroll
    for (int G = 0; G < 3; ++G)
      xv[jt][G] = xptr[G * 128 + (2 * wv + jt) * 16 + fr];

  float hold[2] = {0.f, 0.f};

  for (int it = 0; it < SS; ++it) {
    // A fragments: broadcast h (same addr within each qq group)
    h8v afr[4];
#pragma unroll
    for (int kc = 0; kc < 4; ++kc)
      afr[kc] = *(const h8v*)((const char*)h16 + dir * 256 + kc * 64 + qq * 16);

    float xc[2][3];
#pragma unroll
    for (int jt = 0; jt < 2; ++jt)
#pragma unroll
      for (int G = 0; G < 3; ++G) xc[jt][G] = (float)xv[jt][G];
    if (it < SS - 1) {
      xptr += xstp;
#pragma unroll
      for (int jt = 0; jt < 2; ++jt)
#pragma unroll
        for (int G = 0; G < 3; ++G)
          xv[jt][G] = xptr[G * 128 + (2 * wv + jt) * 16 + fr];
    }

    f32x4 acc[2][3];
#pragma unroll
    for (int jt = 0; jt < 2; ++jt) {
      acc[jt][0] = (f32x4){xc[jt][0] + bias_[jt][0], 0.f, 0.f, 0.f};
      acc[jt][1] = (f32x4){xc[jt][1] + bias_[jt][1], 0.f, 0.f, 0.f};
      acc[jt][2] = (f32x4){bias_[jt][2], 0.f, 0.f, 0.f};
#pragma unroll
      for (int G = 0; G < 3; ++G)
#pragma unroll
        for (int kc = 0; kc < 4; ++kc)
          acc[jt][G] = __builtin_amdgcn_mfma_f32_16x16x32_f16(
              afr[kc], wB[jt][G][kc], acc[jt][G], 0, 0, 0);
    }

    bar_lds();   // all waves' h-frag reads complete before overwrite

    if (qq == 0) {   // D row 0 on lanes 0..15, reg e=0
#pragma unroll
      for (int jt = 0; jt < 2; ++jt) {
        const float r = sigmoidf_(acc[jt][0][0]);
        const float z = sigmoidf_(acc[jt][1][0]);
        const float n = tanhf_(xc[jt][2] + r * acc[jt][2][0]);
        const float hnew = (1.f - z) * n + z * hold[jt];
        hold[jt] = hnew;
        const int j = (2 * wv + jt) * 16 + fr;
        const _Float16 hv = (_Float16)hnew;
        h16[dir][j] = hv;
        hptr[j] = hv;
      }
    }
    hptr += hstp;
    bar_lds();   // h_new visible for next step
  }
}

// ---------------------------------------------------------------------------
// K3: uh[m][n] = sum_k hcat16[m][k] * Wc[k][n]  (fp16 MFMA)
// 128-M tile x full N=160, K=256 staged whole in 64KB swizzled LDS.
// ---------------------------------------------------------------------------
__global__ __launch_bounds__(256) void k3_uhat(
    const _Float16* __restrict__ hcat16, const _Float16* __restrict__ WcT,
    float* __restrict__ uh)
{
  __shared__ __align__(16) _Float16 Hs[128 * 256];   // 64KB
  const int tid = threadIdx.x;
  const int m0 = blockIdx.x * 128;
  const int lane = tid & 63, wv = tid >> 6;
  const int fr = lane & 15, qq = lane >> 4;

  const int srow = tid >> 5;   // 0..7
  const int sch  = tid & 31;   // 16B chunk of 512B row
#pragma unroll
  for (int i = 0; i < 16; ++i) {
    const int r = i * 8 + srow;
    const h8v v = *(const h8v*)(hcat16 + (size_t)(m0 + r) * 256 + sch * 8);
    const int off = (r * 512 + sch * 16) ^ ((r & 7) << 4);
    *(h8v*)((char*)Hs + off) = v;
  }
  __syncthreads();

  f32x4 acc[2][10];
#pragma unroll
  for (int mt = 0; mt < 2; ++mt)
#pragma unroll
    for (int nt = 0; nt < 10; ++nt) acc[mt][nt] = (f32x4){0.f, 0.f, 0.f, 0.f};

#pragma unroll
  for (int kc = 0; kc < 8; ++kc) {
    h8v bf_[10];
#pragma unroll
    for (int nt = 0; nt < 10; ++nt)
      bf_[nt] = *(const h8v*)(WcT + (size_t)(nt * 16 + fr) * 256 + kc * 32 + qq * 8);
    h8v af[2];
#pragma unroll
    for (int mt = 0; mt < 2; ++mt) {
      const int rA = wv * 32 + mt * 16 + fr;
      const int off = (rA * 512 + kc * 64 + qq * 16) ^ ((rA & 7) << 4);
      af[mt] = *(const h8v*)((const char*)Hs + off);
    }
#pragma unroll
    for (int mt = 0; mt < 2; ++mt)
#pragma unroll
      for (int nt = 0; nt < 10; ++nt)
        acc[mt][nt] = __builtin_amdgcn_mfma_f32_16x16x32_f16(
            af[mt], bf_[nt], acc[mt][nt], 0, 0, 0);
  }

#pragma unroll
  for (int mt = 0; mt < 2; ++mt)
#pragma unroll
    for (int nt = 0; nt < 10; ++nt)
#pragma unroll
      for (int e = 0; e < 4; ++e) {
        const int m = m0 + wv * 32 + mt * 16 + qq * 4 + e;
        uh[(size_t)m * NCDC + nt * 16 + fr] = acc[mt][nt][e];
      }
}

// ---------------------------------------------------------------------------
// K4: dynamic routing + final linear. One block per batch element.
// ---------------------------------------------------------------------------
__global__ __launch_bounds__(256) void k4_route(
    const float* __restrict__ uhat, const float* __restrict__ Wl,
    const float* __restrict__ bl, float* __restrict__ outp)
{
  const int b = blockIdx.x;
  const int t = threadIdx.x;
  __shared__ float blog[NC][SS + 1];
  __shared__ float cbuf[NC][SS + 1];
  __shared__ float vout[NC][DC];
  __shared__ float red0[256], red1[256];

  const float* __restrict__ u = uhat + (size_t)b * SS * NCDC;

#pragma unroll
  for (int i = 0; i < NC; ++i) blog[i][t] = 0.f;
  __syncthreads();

  const int ci = t >> 4, ck = t & 15;
  float myval = 0.f;

  for (int it = 0; it < 5; ++it) {
    float m = blog[0][t];
#pragma unroll
    for (int i = 1; i < NC; ++i) m = fmaxf(m, blog[i][t]);
    float e[NC];
    float sum = 0.f;
#pragma unroll
    for (int i = 0; i < NC; ++i) { e[i] = __expf(blog[i][t] - m); sum += e[i]; }
    const float inv = __builtin_amdgcn_rcpf(sum);
#pragma unroll
    for (int i = 0; i < NC; ++i) cbuf[i][t] = e[i] * inv;
    __syncthreads();

    if (t < NCDC) {
      float acc = 0.f;
#pragma unroll 4
      for (int jj = 0; jj < SS; ++jj)
        acc += cbuf[ci][jj] * u[(size_t)jj * NCDC + t];
      float ss = acc * acc;
      ss += __shfl_xor(ss, 1);
      ss += __shfl_xor(ss, 2);
      ss += __shfl_xor(ss, 4);
      ss += __shfl_xor(ss, 8);
      myval = acc * __builtin_amdgcn_rsqf(ss + CAP_EPS);
      vout[ci][ck] = myval;
    }
    __syncthreads();

    if (it < 4) {
      const float* ur = u + (size_t)t * NCDC;
#pragma unroll
      for (int i = 0; i < NC; ++i) {
        float dot = 0.f;
#pragma unroll
        for (int k = 0; k < DC; ++k) dot += ur[i * DC + k] * vout[i][k];
        blog[i][t] += dot;
      }
      __syncthreads();
    }
  }

  float p0 = 0.f, p1 = 0.f;
  if (t < NCDC) { p0 = myval * Wl[2 * t]; p1 = myval * Wl[2 * t + 1]; }
  red0[t] = p0; red1[t] = p1;
  __syncthreads();
  for (int off = 128; off >= 1; off >>= 1) {
    if (t < off) { red0[t] += red0[t + off]; red1[t] += red1[t + off]; }
    __syncthreads();
  }
  if (t == 0) {
    outp[2 * b + 0] = red0[0] + bl[0];
    outp[2 * b + 1] = red1[0] + bl[1];
  }
}

extern "C" void kernel_launch(void* const* d_in, const int* in_sizes, int n_in,
                              void* d_out, int out_size, void* d_ws, size_t ws_size,
                              hipStream_t stream) {
  (void)in_sizes; (void)n_in; (void)out_size; (void)ws_size;
  const int*   x    = (const int*)  d_in[0];
  const float* emb  = (const float*)d_in[1];
  const float* wif  = (const float*)d_in[2];
  const float* whf  = (const float*)d_in[3];
  const float* bif  = (const float*)d_in[4];
  const float* bhf  = (const float*)d_in[5];
  const float* wib  = (const float*)d_in[6];
  const float* whb  = (const float*)d_in[7];
  const float* bib  = (const float*)d_in[8];
  const float* bhb  = (const float*)d_in[9];
  const float* Wc   = (const float*)d_in[10];
  const float* Wl   = (const float*)d_in[11];
  const float* bl   = (const float*)d_in[12];
  float* out = (float*)d_out;

  char* base = (char*)d_ws;
  _Float16* xp16   = (_Float16*)base;                       //  50.33 MB
  _Float16* hcat16 = (_Float16*)(base + 50331648);          //  16.78 MB
  float*    uh     = (float*)   (base + 67108864);          //  20.97 MB
  _Float16* A16    = (_Float16*)(base + 88080384);          //  20.97 MB
  _Float16* Bw16   = (_Float16*)(base + 109051904);         //   0.49 MB
  _Float16* WcT    = (_Float16*)(base + 109543424);         //   0.08 MB

  hipLaunchKernelGGL(k0_prep, dim3(33696), dim3(64), 0, stream,
                     x, emb, wif, wib, Wc, A16, Bw16, WcT);
  hipLaunchKernelGGL(k1_xproj, dim3(256, 6), dim3(256), 0, stream,
                     A16, Bw16, bif, bib, xp16);
  hipLaunchKernelGGL(k2_gru, dim3(128), dim3(512), 0, stream,
                     xp16, whf, whb, bhf, bhb, hcat16);
  hipLaunchKernelGGL(k3_uhat, dim3(256), dim3(256), 0, stream,
                     hcat16, WcT, uh);
  hipLaunchKernelGGL(k4_route, dim3(128), dim3(256), 0, stream,
                     uh, Wl, bl, out);
}

// Round 10
// 252.092 us; speedup vs baseline: 1.5236x; 1.2476x over previous
//
#include <hip/hip_runtime.h>
#include <cmath>

#define DW 300
#define HH 128
#define G3 384
#define GN 768
#define SS 256
#define NB 128
#define NC 10
#define DC 16
#define NCDC 160
#define CAP_EPS 1e-7f
#define KP 320

typedef _Float16 h8v __attribute__((ext_vector_type(8)));
typedef _Float16 h4v __attribute__((ext_vector_type(4)));
typedef float f32x4 __attribute__((ext_vector_type(4)));

__device__ __forceinline__ float rcp_(float x) { return __builtin_amdgcn_rcpf(x); }
__device__ __forceinline__ float sigmoidf_(float x) {
  return rcp_(1.0f + __expf(-x));
}
__device__ __forceinline__ float tanhf_(float x) {
  return 1.0f - 2.0f * rcp_(__expf(2.0f * x) + 1.0f);
}
// LDS-only barrier: don't drain vmcnt, so global loads/stores stay in flight.
__device__ __forceinline__ void bar_lds() {
  asm volatile("s_waitcnt lgkmcnt(0)\n\ts_barrier" ::: "memory");
}

// ---------------------------------------------------------------------------
// K0: gather emb rows -> A16[32768][320] fp16 (K padded 300->320 with zeros),
// convert w_ih (f+b) -> Bw16[768][320], transpose W_cap -> WcT[160][256].
// ---------------------------------------------------------------------------
__global__ __launch_bounds__(64) void k0_prep(
    const int* __restrict__ x, const float* __restrict__ emb,
    const float* __restrict__ wif, const float* __restrict__ wib,
    const float* __restrict__ Wc,
    _Float16* __restrict__ A16, _Float16* __restrict__ Bw16,
    _Float16* __restrict__ WcT)
{
  const int row = blockIdx.x;
  const int t = threadIdx.x;
  if (row < 33536) {
    const float* __restrict__ src;
    _Float16* __restrict__ dst;
    if (row < 32768) {
      src = emb + (size_t)x[(row & 127) * SS + (row >> 7)] * DW;
      dst = A16 + (size_t)row * KP;
    } else {
      const int n = row - 32768;
      src = (n < G3) ? (wif + (size_t)n * DW) : (wib + (size_t)(n - G3) * DW);
      dst = Bw16 + (size_t)n * KP;
    }
#pragma unroll
    for (int p = 0; p < 2; ++p) {
      const int idx = p * 64 + t;
      if (idx < 75) {
        const float4 v = *(const float4*)(src + idx * 4);
        h4v o = {(_Float16)v.x, (_Float16)v.y, (_Float16)v.z, (_Float16)v.w};
        *(h4v*)(dst + idx * 4) = o;
      }
    }
    if (t < 5) {
      h4v z = {(_Float16)0.f, (_Float16)0.f, (_Float16)0.f, (_Float16)0.f};
      *(h4v*)(dst + 300 + t * 4) = z;
    }
  } else {
    const int n = row - 33536;   // 0..159
    _Float16* __restrict__ dst = WcT + (size_t)n * 256;
#pragma unroll
    for (int p = 0; p < 4; ++p) {
      const int k = p * 64 + t;
      dst[k] = (_Float16)Wc[(size_t)k * NCDC + n];
    }
  }
}

// ---------------------------------------------------------------------------
// K1: fp16 MFMA GEMM for x-projection.
// m-tile (128) == one timestep s, all 128 batches; n-tile (128) == one (dir,G).
// Epilogue: bias add + fp16 repack via LDS, store to
// xp16[dir][b][s][G*128+j]  (contiguous 768B per (seq,step) for k2).
// ---------------------------------------------------------------------------
__global__ __launch_bounds__(256) void k1_xproj(
    const _Float16* __restrict__ A16, const _Float16* __restrict__ Bw16,
    const float* __restrict__ bf, const float* __restrict__ bb,
    _Float16* __restrict__ xp16)
{
  __shared__ __align__(16) _Float16 Asb[128 * 64];
  __shared__ __align__(16) _Float16 Bsb[128 * 64];
  __shared__ __align__(16) _Float16 Ls[128 * 132];   // repack, padded stride
  const int tid = threadIdx.x;
  const int s_idx = blockIdx.x;          // timestep
  const int n0 = blockIdx.y * 128;       // (dir, G)
  const int m0 = s_idx * 128;
  const int dir = (n0 >= G3) ? 1 : 0;
  const int G = (n0 >> 7) - dir * 3;

  const int lane = tid & 63;
  const int wv = tid >> 6, wm = wv >> 1, wn = wv & 1;
  const int fr = lane & 15, kc4 = lane >> 4;

  const int srow = tid >> 3;   // 0..31 (+i*32)
  const int sch  = tid & 7;    // 16B chunk within 128B row

  f32x4 acc[4][4];
#pragma unroll
  for (int i = 0; i < 4; ++i)
#pragma unroll
    for (int j = 0; j < 4; ++j) acc[i][j] = (f32x4){0.f, 0.f, 0.f, 0.f};

  h8v ra[4], rb[4];
#pragma unroll
  for (int i = 0; i < 4; ++i) {
    const int r = i * 32 + srow;
    ra[i] = *(const h8v*)(A16 + (size_t)(m0 + r) * KP + sch * 8);
    rb[i] = *(const h8v*)(Bw16 + (size_t)(n0 + r) * KP + sch * 8);
  }

  for (int kt = 0; kt < 5; ++kt) {
    if (kt) bar_lds();                    // prev frag reads done
#pragma unroll
    for (int i = 0; i < 4; ++i) {
      const int r = i * 32 + srow;
      const int off = (r * 128 + sch * 16) ^ ((r & 7) << 4);
      *(h8v*)((char*)Asb + off) = ra[i];
      *(h8v*)((char*)Bsb + off) = rb[i];
    }
    if (kt < 4) {
      const int kb = (kt + 1) * 64;
#pragma unroll
      for (int i = 0; i < 4; ++i) {
        const int r = i * 32 + srow;
        ra[i] = *(const h8v*)(A16 + (size_t)(m0 + r) * KP + kb + sch * 8);
        rb[i] = *(const h8v*)(Bw16 + (size_t)(n0 + r) * KP + kb + sch * 8);
      }
    }
    bar_lds();                            // staged tile visible

    h8v af[4][2], bfv[4][2];
#pragma unroll
    for (int mf = 0; mf < 4; ++mf) {
      const int rA = wm * 64 + mf * 16 + fr;
#pragma unroll
      for (int ks = 0; ks < 2; ++ks) {
        const int off = (rA * 128 + ks * 64 + kc4 * 16) ^ ((rA & 7) << 4);
        af[mf][ks] = *(const h8v*)((const char*)Asb + off);
      }
    }
#pragma unroll
    for (int nf = 0; nf < 4; ++nf) {
      const int rB = wn * 64 + nf * 16 + fr;
#pragma unroll
      for (int ks = 0; ks < 2; ++ks) {
        const int off = (rB * 128 + ks * 64 + kc4 * 16) ^ ((rB & 7) << 4);
        bfv[nf][ks] = *(const h8v*)((const char*)Bsb + off);
      }
    }
#pragma unroll
    for (int ks = 0; ks < 2; ++ks)
#pragma unroll
      for (int mf = 0; mf < 4; ++mf)
#pragma unroll
        for (int nf = 0; nf < 4; ++nf)
          acc[mf][nf] = __builtin_amdgcn_mfma_f32_16x16x32_f16(
              af[mf][ks], bfv[nf][ks], acc[mf][nf], 0, 0, 0);
  }

  // ---- epilogue: bias + fp16 repack in LDS, then coalesced store ----
  const float* __restrict__ bsrc = (n0 < G3) ? (bf + n0) : (bb + (n0 - G3));
  float bval[4];
#pragma unroll
  for (int nf = 0; nf < 4; ++nf) bval[nf] = bsrc[wn * 64 + nf * 16 + fr];

#pragma unroll
  for (int mf = 0; mf < 4; ++mf)
#pragma unroll
    for (int e = 0; e < 4; ++e) {
      const int r = wm * 64 + mf * 16 + kc4 * 4 + e;   // batch b
#pragma unroll
      for (int nf = 0; nf < 4; ++nf) {
        const int c = wn * 64 + nf * 16 + fr;          // j within gate
        Ls[r * 132 + c] = (_Float16)(acc[mf][nf][e] + bval[nf]);
      }
    }
  __syncthreads();

  // 256 threads: unit = (row b, half): 128B contiguous per unit
  {
    const int r = tid >> 1;
    const int hf = tid & 1;
    _Float16* __restrict__ dst =
        xp16 + ((size_t)(dir * NB + r) * SS + s_idx) * G3 + G * 128 + hf * 64;
    const _Float16* srcl = &Ls[r * 132 + hf * 64];
#pragma unroll
    for (int i = 0; i < 8; ++i)
      *(h8v*)(dst + i * 8) = *(const h8v*)(srcl + i * 8);
  }
}

// ---------------------------------------------------------------------------
// K2: GRU recurrence via MFMA. 256 blocks = (dir, b), full chip; 8 waves
// (512 thr, 2 waves/SIMD). Wave jg owns ONE j-tile (16 units), all 3 gates:
// 12 MFMA + ~45 VALU per step (half of R9's per-wave work).
// PROVEN two-barrier protocol: read-all -> bar -> gate+write -> bar.
// Gates computed on ALL lanes (D rows identical, A-rows broadcast h);
// stores masked to qq==0.
// ---------------------------------------------------------------------------
__global__ __launch_bounds__(512) void k2_gru(
    const _Float16* __restrict__ xp16,
    const float* __restrict__ whf, const float* __restrict__ whb,
    const float* __restrict__ bhf, const float* __restrict__ bhb,
    _Float16* __restrict__ hcat16)
{
  const int blk = blockIdx.x;      // 0..255
  const int dir = blk >> 7;
  const int b   = blk & 127;
  const int tid = threadIdx.x;
  const int jg  = tid >> 6;        // wave = j-tile owner, 0..7
  const int lane = tid & 63;
  const int fr = lane & 15;
  const int qq = lane >> 4;

  const float* __restrict__ wh = dir ? whb : whf;
  const float* __restrict__ bh = dir ? bhb : bhf;

  // B fragments (w_hh^T) for this wave's j-tile, all 3 gates; persistent.
  h8v wB[3][4];
  float bias_[3];
#pragma unroll
  for (int G = 0; G < 3; ++G) {
    const int row = G * HH + jg * 16 + fr;
    const float* __restrict__ p = wh + (size_t)row * HH;
#pragma unroll
    for (int kc = 0; kc < 4; ++kc) {
      const float* q = p + kc * 32 + qq * 8;
      const float4 u0 = *(const float4*)(q);
      const float4 u1 = *(const float4*)(q + 4);
      wB[G][kc] = (h8v){(_Float16)u0.x, (_Float16)u0.y, (_Float16)u0.z,
                        (_Float16)u0.w, (_Float16)u1.x, (_Float16)u1.y,
                        (_Float16)u1.z, (_Float16)u1.w};
    }
    bias_[G] = bh[G * HH + jg * 16 + fr];
  }

  __shared__ __align__(16) _Float16 h16[HH];   // 256 B
  if (tid < 16) *(h8v*)(h16 + tid * 8) = (h8v){0, 0, 0, 0, 0, 0, 0, 0};
  __syncthreads();

  const int stp = dir ? -1 : 1;
  int s = dir ? (SS - 1) : 0;
  const ptrdiff_t xstp = (ptrdiff_t)stp * G3;
  const ptrdiff_t hstp = (ptrdiff_t)stp * 256;
  const _Float16* __restrict__ xptr =
      xp16 + (size_t)(dir * NB + b) * SS * G3 + (size_t)s * G3;
  _Float16* __restrict__ hptr =
      hcat16 + ((size_t)b * SS + s) * 256 + dir * HH;

  _Float16 xv[3];
#pragma unroll
  for (int G = 0; G < 3; ++G)
    xv[G] = xptr[G * 128 + jg * 16 + fr];

  float hold = 0.f;

  for (int it = 0; it < SS; ++it) {
    // A fragments: broadcast h (same addr within each qq group)
    h8v afr[4];
#pragma unroll
    for (int kc = 0; kc < 4; ++kc)
      afr[kc] = *(const h8v*)((const char*)h16 + kc * 64 + qq * 16);

    float xc[3];
#pragma unroll
    for (int G = 0; G < 3; ++G) xc[G] = (float)xv[G];
    if (it < SS - 1) {
      xptr += xstp;
#pragma unroll
      for (int G = 0; G < 3; ++G)
        xv[G] = xptr[G * 128 + jg * 16 + fr];
    }

    f32x4 acc[3];
    acc[0] = (f32x4){xc[0] + bias_[0], 0.f, 0.f, 0.f};
    acc[1] = (f32x4){xc[1] + bias_[1], 0.f, 0.f, 0.f};
    acc[2] = (f32x4){bias_[2], 0.f, 0.f, 0.f};
#pragma unroll
    for (int G = 0; G < 3; ++G)
#pragma unroll
      for (int kc = 0; kc < 4; ++kc)
        acc[G] = __builtin_amdgcn_mfma_f32_16x16x32_f16(
            afr[kc], wB[G][kc], acc[G], 0, 0, 0);

    bar_lds();   // all waves' h-frag reads complete before overwrite

    // gates: all lanes compute (rows identical); stores masked to qq==0
    const float r = sigmoidf_(acc[0][0]);
    const float z = sigmoidf_(acc[1][0]);
    const float n = tanhf_(xc[2] + r * acc[2][0]);
    const float hnew = (1.f - z) * n + z * hold;
    hold = hnew;
    if (qq == 0) {
      const int j = jg * 16 + fr;
      const _Float16 hv = (_Float16)hnew;
      h16[j] = hv;
      hptr[j] = hv;
    }
    hptr += hstp;
    bar_lds();   // h_new visible for next step
  }
}

// ---------------------------------------------------------------------------
// K3: uh[m][n] = sum_k hcat16[m][k] * Wc[k][n]  (fp16 MFMA)
// 128-M tile x full N=160, K=256 staged whole in 64KB swizzled LDS.
// ---------------------------------------------------------------------------
__global__ __launch_bounds__(256) void k3_uhat(
    const _Float16* __restrict__ hcat16, const _Float16* __restrict__ WcT,
    float* __restrict__ uh)
{
  __shared__ __align__(16) _Float16 Hs[128 * 256];   // 64KB
  const int tid = threadIdx.x;
  const int m0 = blockIdx.x * 128;
  const int lane = tid & 63, wv = tid >> 6;
  const int fr = lane & 15, qq = lane >> 4;

  const int srow = tid >> 5;   // 0..7
  const int sch  = tid & 31;   // 16B chunk of 512B row
#pragma unroll
  for (int i = 0; i < 16; ++i) {
    const int r = i * 8 + srow;
    const h8v v = *(const h8v*)(hcat16 + (size_t)(m0 + r) * 256 + sch * 8);
    const int off = (r * 512 + sch * 16) ^ ((r & 7) << 4);
    *(h8v*)((char*)Hs + off) = v;
  }
  __syncthreads();

  f32x4 acc[2][10];
#pragma unroll
  for (int mt = 0; mt < 2; ++mt)
#pragma unroll
    for (int nt = 0; nt < 10; ++nt) acc[mt][nt] = (f32x4){0.f, 0.f, 0.f, 0.f};

#pragma unroll
  for (int kc = 0; kc < 8; ++kc) {
    h8v bf_[10];
#pragma unroll
    for (int nt = 0; nt < 10; ++nt)
      bf_[nt] = *(const h8v*)(WcT + (size_t)(nt * 16 + fr) * 256 + kc * 32 + qq * 8);
    h8v af[2];
#pragma unroll
    for (int mt = 0; mt < 2; ++mt) {
      const int rA = wv * 32 + mt * 16 + fr;
      const int off = (rA * 512 + kc * 64 + qq * 16) ^ ((rA & 7) << 4);
      af[mt] = *(const h8v*)((const char*)Hs + off);
    }
#pragma unroll
    for (int mt = 0; mt < 2; ++mt)
#pragma unroll
      for (int nt = 0; nt < 10; ++nt)
        acc[mt][nt] = __builtin_amdgcn_mfma_f32_16x16x32_f16(
            af[mt], bf_[nt], acc[mt][nt], 0, 0, 0);
  }

#pragma unroll
  for (int mt = 0; mt < 2; ++mt)
#pragma unroll
    for (int nt = 0; nt < 10; ++nt)
#pragma unroll
      for (int e = 0; e < 4; ++e) {
        const int m = m0 + wv * 32 + mt * 16 + qq * 4 + e;
        uh[(size_t)m * NCDC + nt * 16 + fr] = acc[mt][nt][e];
      }
}

// ---------------------------------------------------------------------------
// K4: dynamic routing + final linear. One block per batch element.
// ---------------------------------------------------------------------------
__global__ __launch_bounds__(256) void k4_route(
    const float* __restrict__ uhat, const float* __restrict__ Wl,
    const float* __restrict__ bl, float* __restrict__ outp)
{
  const int b = blockIdx.x;
  const int t = threadIdx.x;
  __shared__ float blog[NC][SS + 1];
  __shared__ float cbuf[NC][SS + 1];
  __shared__ float vout[NC][DC];
  __shared__ float red0[256], red1[256];

  const float* __restrict__ u = uhat + (size_t)b * SS * NCDC;

#pragma unroll
  for (int i = 0; i < NC; ++i) blog[i][t] = 0.f;
  __syncthreads();

  const int ci = t >> 4, ck = t & 15;
  float myval = 0.f;

  for (int it = 0; it < 5; ++it) {
    float m = blog[0][t];
#pragma unroll
    for (int i = 1; i < NC; ++i) m = fmaxf(m, blog[i][t]);
    float e[NC];
    float sum = 0.f;
#pragma unroll
    for (int i = 0; i < NC; ++i) { e[i] = __expf(blog[i][t] - m); sum += e[i]; }
    const float inv = __builtin_amdgcn_rcpf(sum);
#pragma unroll
    for (int i = 0; i < NC; ++i) cbuf[i][t] = e[i] * inv;
    __syncthreads();

    if (t < NCDC) {
      float acc = 0.f;
#pragma unroll 4
      for (int jj = 0; jj < SS; ++jj)
        acc += cbuf[ci][jj] * u[(size_t)jj * NCDC + t];
      float ss = acc * acc;
      ss += __shfl_xor(ss, 1);
      ss += __shfl_xor(ss, 2);
      ss += __shfl_xor(ss, 4);
      ss += __shfl_xor(ss, 8);
      myval = acc * __builtin_amdgcn_rsqf(ss + CAP_EPS);
      vout[ci][ck] = myval;
    }
    __syncthreads();

    if (it < 4) {
      const float* ur = u + (size_t)t * NCDC;
#pragma unroll
      for (int i = 0; i < NC; ++i) {
        float dot = 0.f;
#pragma unroll
        for (int k = 0; k < DC; ++k) dot += ur[i * DC + k] * vout[i][k];
        blog[i][t] += dot;
      }
      __syncthreads();
    }
  }

  float p0 = 0.f, p1 = 0.f;
  if (t < NCDC) { p0 = myval * Wl[2 * t]; p1 = myval * Wl[2 * t + 1]; }
  red0[t] = p0; red1[t] = p1;
  __syncthreads();
  for (int off = 128; off >= 1; off >>= 1) {
    if (t < off) { red0[t] += red0[t + off]; red1[t] += red1[t + off]; }
    __syncthreads();
  }
  if (t == 0) {
    outp[2 * b + 0] = red0[0] + bl[0];
    outp[2 * b + 1] = red1[0] + bl[1];
  }
}

extern "C" void kernel_launch(void* const* d_in, const int* in_sizes, int n_in,
                              void* d_out, int out_size, void* d_ws, size_t ws_size,
                              hipStream_t stream) {
  (void)in_sizes; (void)n_in; (void)out_size; (void)ws_size;
  const int*   x    = (const int*)  d_in[0];
  const float* emb  = (const float*)d_in[1];
  const float* wif  = (const float*)d_in[2];
  const float* whf  = (const float*)d_in[3];
  const float* bif  = (const float*)d_in[4];
  const float* bhf  = (const float*)d_in[5];
  const float* wib  = (const float*)d_in[6];
  const float* whb  = (const float*)d_in[7];
  const float* bib  = (const float*)d_in[8];
  const float* bhb  = (const float*)d_in[9];
  const float* Wc   = (const float*)d_in[10];
  const float* Wl   = (const float*)d_in[11];
  const float* bl   = (const float*)d_in[12];
  float* out = (float*)d_out;

  char* base = (char*)d_ws;
  _Float16* xp16   = (_Float16*)base;                       //  50.33 MB
  _Float16* hcat16 = (_Float16*)(base + 50331648);          //  16.78 MB
  float*    uh     = (float*)   (base + 67108864);          //  20.97 MB
  _Float16* A16    = (_Float16*)(base + 88080384);          //  20.97 MB
  _Float16* Bw16   = (_Float16*)(base + 109051904);         //   0.49 MB
  _Float16* WcT    = (_Float16*)(base + 109543424);         //   0.08 MB

  hipLaunchKernelGGL(k0_prep, dim3(33696), dim3(64), 0, stream,
                     x, emb, wif, wib, Wc, A16, Bw16, WcT);
  hipLaunchKernelGGL(k1_xproj, dim3(256, 6), dim3(256), 0, stream,
                     A16, Bw16, bif, bib, xp16);
  hipLaunchKernelGGL(k2_gru, dim3(256), dim3(512), 0, stream,
                     xp16, whf, whb, bhf, bhb, hcat16);
  hipLaunchKernelGGL(k3_uhat, dim3(256), dim3(256), 0, stream,
                     hcat16, WcT, uh);
  hipLaunchKernelGGL(k4_route, dim3(128), dim3(256), 0, stream,
                     uh, Wl, bl, out);
}

// Round 11
// 217.693 us; speedup vs baseline: 1.7643x; 1.1580x over previous
//
#include <hip/hip_runtime.h>
#include <cmath>

#define DW 300
#define HH 128
#define G3 384
#define GN 768
#define SS 256
#define NB 128
#define NC 10
#define DC 16
#define NCDC 160
#define CAP_EPS 1e-7f
#define KP 320

typedef _Float16 h8v __attribute__((ext_vector_type(8)));
typedef _Float16 h4v __attribute__((ext_vector_type(4)));
typedef float f32x4 __attribute__((ext_vector_type(4)));

__device__ __forceinline__ float rcp_(float x) { return __builtin_amdgcn_rcpf(x); }
__device__ __forceinline__ float sigmoidf_(float x) {
  return rcp_(1.0f + __expf(-x));
}
__device__ __forceinline__ float tanhf_(float x) {
  return 1.0f - 2.0f * rcp_(__expf(2.0f * x) + 1.0f);
}
// LDS-only barrier: don't drain vmcnt, so global loads/stores stay in flight.
__device__ __forceinline__ void bar_lds() {
  asm volatile("s_waitcnt lgkmcnt(0)\n\ts_barrier" ::: "memory");
}

// ---------------------------------------------------------------------------
// K0: gather emb rows -> A16[32768][320] fp16 (K padded 300->320 with zeros),
// convert w_ih (f+b) -> Bw16[768][320], transpose W_cap -> WcT[160][256].
// ---------------------------------------------------------------------------
__global__ __launch_bounds__(64) void k0_prep(
    const int* __restrict__ x, const float* __restrict__ emb,
    const float* __restrict__ wif, const float* __restrict__ wib,
    const float* __restrict__ Wc,
    _Float16* __restrict__ A16, _Float16* __restrict__ Bw16,
    _Float16* __restrict__ WcT)
{
  const int row = blockIdx.x;
  const int t = threadIdx.x;
  if (row < 33536) {
    const float* __restrict__ src;
    _Float16* __restrict__ dst;
    if (row < 32768) {
      src = emb + (size_t)x[(row & 127) * SS + (row >> 7)] * DW;
      dst = A16 + (size_t)row * KP;
    } else {
      const int n = row - 32768;
      src = (n < G3) ? (wif + (size_t)n * DW) : (wib + (size_t)(n - G3) * DW);
      dst = Bw16 + (size_t)n * KP;
    }
#pragma unroll
    for (int p = 0; p < 2; ++p) {
      const int idx = p * 64 + t;
      if (idx < 75) {
        const float4 v = *(const float4*)(src + idx * 4);
        h4v o = {(_Float16)v.x, (_Float16)v.y, (_Float16)v.z, (_Float16)v.w};
        *(h4v*)(dst + idx * 4) = o;
      }
    }
    if (t < 5) {
      h4v z = {(_Float16)0.f, (_Float16)0.f, (_Float16)0.f, (_Float16)0.f};
      *(h4v*)(dst + 300 + t * 4) = z;
    }
  } else {
    const int n = row - 33536;   // 0..159
    _Float16* __restrict__ dst = WcT + (size_t)n * 256;
#pragma unroll
    for (int p = 0; p < 4; ++p) {
      const int k = p * 64 + t;
      dst[k] = (_Float16)Wc[(size_t)k * NCDC + n];
    }
  }
}

// ---------------------------------------------------------------------------
// K1: fp16 MFMA GEMM for x-projection.
// m-tile (128) == one timestep s, all 128 batches; n-tile (128) == one (dir,G).
// Epilogue: bias add + fp16 repack via LDS, store to
// xp16[dir][b][s][G*128+j]  (contiguous 768B per (seq,step) for k2).
// ---------------------------------------------------------------------------
__global__ __launch_bounds__(256) void k1_xproj(
    const _Float16* __restrict__ A16, const _Float16* __restrict__ Bw16,
    const float* __restrict__ bf, const float* __restrict__ bb,
    _Float16* __restrict__ xp16)
{
  __shared__ __align__(16) _Float16 Asb[128 * 64];
  __shared__ __align__(16) _Float16 Bsb[128 * 64];
  __shared__ __align__(16) _Float16 Ls[128 * 132];   // repack, padded stride
  const int tid = threadIdx.x;
  const int s_idx = blockIdx.x;          // timestep
  const int n0 = blockIdx.y * 128;       // (dir, G)
  const int m0 = s_idx * 128;
  const int dir = (n0 >= G3) ? 1 : 0;
  const int G = (n0 >> 7) - dir * 3;

  const int lane = tid & 63;
  const int wv = tid >> 6, wm = wv >> 1, wn = wv & 1;
  const int fr = lane & 15, kc4 = lane >> 4;

  const int srow = tid >> 3;   // 0..31 (+i*32)
  const int sch  = tid & 7;    // 16B chunk within 128B row

  f32x4 acc[4][4];
#pragma unroll
  for (int i = 0; i < 4; ++i)
#pragma unroll
    for (int j = 0; j < 4; ++j) acc[i][j] = (f32x4){0.f, 0.f, 0.f, 0.f};

  h8v ra[4], rb[4];
#pragma unroll
  for (int i = 0; i < 4; ++i) {
    const int r = i * 32 + srow;
    ra[i] = *(const h8v*)(A16 + (size_t)(m0 + r) * KP + sch * 8);
    rb[i] = *(const h8v*)(Bw16 + (size_t)(n0 + r) * KP + sch * 8);
  }

  for (int kt = 0; kt < 5; ++kt) {
    if (kt) bar_lds();                    // prev frag reads done
#pragma unroll
    for (int i = 0; i < 4; ++i) {
      const int r = i * 32 + srow;
      const int off = (r * 128 + sch * 16) ^ ((r & 7) << 4);
      *(h8v*)((char*)Asb + off) = ra[i];
      *(h8v*)((char*)Bsb + off) = rb[i];
    }
    if (kt < 4) {
      const int kb = (kt + 1) * 64;
#pragma unroll
      for (int i = 0; i < 4; ++i) {
        const int r = i * 32 + srow;
        ra[i] = *(const h8v*)(A16 + (size_t)(m0 + r) * KP + kb + sch * 8);
        rb[i] = *(const h8v*)(Bw16 + (size_t)(n0 + r) * KP + kb + sch * 8);
      }
    }
    bar_lds();                            // staged tile visible

    h8v af[4][2], bfv[4][2];
#pragma unroll
    for (int mf = 0; mf < 4; ++mf) {
      const int rA = wm * 64 + mf * 16 + fr;
#pragma unroll
      for (int ks = 0; ks < 2; ++ks) {
        const int off = (rA * 128 + ks * 64 + kc4 * 16) ^ ((rA & 7) << 4);
        af[mf][ks] = *(const h8v*)((const char*)Asb + off);
      }
    }
#pragma unroll
    for (int nf = 0; nf < 4; ++nf) {
      const int rB = wn * 64 + nf * 16 + fr;
#pragma unroll
      for (int ks = 0; ks < 2; ++ks) {
        const int off = (rB * 128 + ks * 64 + kc4 * 16) ^ ((rB & 7) << 4);
        bfv[nf][ks] = *(const h8v*)((const char*)Bsb + off);
      }
    }
#pragma unroll
    for (int ks = 0; ks < 2; ++ks)
#pragma unroll
      for (int mf = 0; mf < 4; ++mf)
#pragma unroll
        for (int nf = 0; nf < 4; ++nf)
          acc[mf][nf] = __builtin_amdgcn_mfma_f32_16x16x32_f16(
              af[mf][ks], bfv[nf][ks], acc[mf][nf], 0, 0, 0);
  }

  // ---- epilogue: bias + fp16 repack in LDS, then coalesced store ----
  const float* __restrict__ bsrc = (n0 < G3) ? (bf + n0) : (bb + (n0 - G3));
  float bval[4];
#pragma unroll
  for (int nf = 0; nf < 4; ++nf) bval[nf] = bsrc[wn * 64 + nf * 16 + fr];

#pragma unroll
  for (int mf = 0; mf < 4; ++mf)
#pragma unroll
    for (int e = 0; e < 4; ++e) {
      const int r = wm * 64 + mf * 16 + kc4 * 4 + e;   // batch b
#pragma unroll
      for (int nf = 0; nf < 4; ++nf) {
        const int c = wn * 64 + nf * 16 + fr;          // j within gate
        Ls[r * 132 + c] = (_Float16)(acc[mf][nf][e] + bval[nf]);
      }
    }
  __syncthreads();

  // 256 threads: unit = (row b, half): 128B contiguous per unit
  {
    const int r = tid >> 1;
    const int hf = tid & 1;
    _Float16* __restrict__ dst =
        xp16 + ((size_t)(dir * NB + r) * SS + s_idx) * G3 + G * 128 + hf * 64;
    const _Float16* srcl = &Ls[r * 132 + hf * 64];
#pragma unroll
    for (int i = 0; i < 8; ++i)
      *(h8v*)(dst + i * 8) = *(const h8v*)(srcl + i * 8);
  }
}

// ---------------------------------------------------------------------------
// K2: GRU recurrence via MFMA. 256 blocks = (dir, b), full chip; 8 waves
// (512 thr, 2 waves/SIMD). Wave jg owns ONE j-tile (16 units), all 3 gates.
// PROVEN two-barrier protocol. UNCHANGED from round 10 (125 us).
// ---------------------------------------------------------------------------
__global__ __launch_bounds__(512) void k2_gru(
    const _Float16* __restrict__ xp16,
    const float* __restrict__ whf, const float* __restrict__ whb,
    const float* __restrict__ bhf, const float* __restrict__ bhb,
    _Float16* __restrict__ hcat16)
{
  const int blk = blockIdx.x;      // 0..255
  const int dir = blk >> 7;
  const int b   = blk & 127;
  const int tid = threadIdx.x;
  const int jg  = tid >> 6;        // wave = j-tile owner, 0..7
  const int lane = tid & 63;
  const int fr = lane & 15;
  const int qq = lane >> 4;

  const float* __restrict__ wh = dir ? whb : whf;
  const float* __restrict__ bh = dir ? bhb : bhf;

  h8v wB[3][4];
  float bias_[3];
#pragma unroll
  for (int G = 0; G < 3; ++G) {
    const int row = G * HH + jg * 16 + fr;
    const float* __restrict__ p = wh + (size_t)row * HH;
#pragma unroll
    for (int kc = 0; kc < 4; ++kc) {
      const float* q = p + kc * 32 + qq * 8;
      const float4 u0 = *(const float4*)(q);
      const float4 u1 = *(const float4*)(q + 4);
      wB[G][kc] = (h8v){(_Float16)u0.x, (_Float16)u0.y, (_Float16)u0.z,
                        (_Float16)u0.w, (_Float16)u1.x, (_Float16)u1.y,
                        (_Float16)u1.z, (_Float16)u1.w};
    }
    bias_[G] = bh[G * HH + jg * 16 + fr];
  }

  __shared__ __align__(16) _Float16 h16[HH];   // 256 B
  if (tid < 16) *(h8v*)(h16 + tid * 8) = (h8v){0, 0, 0, 0, 0, 0, 0, 0};
  __syncthreads();

  const int stp = dir ? -1 : 1;
  int s = dir ? (SS - 1) : 0;
  const ptrdiff_t xstp = (ptrdiff_t)stp * G3;
  const ptrdiff_t hstp = (ptrdiff_t)stp * 256;
  const _Float16* __restrict__ xptr =
      xp16 + (size_t)(dir * NB + b) * SS * G3 + (size_t)s * G3;
  _Float16* __restrict__ hptr =
      hcat16 + ((size_t)b * SS + s) * 256 + dir * HH;

  _Float16 xv[3];
#pragma unroll
  for (int G = 0; G < 3; ++G)
    xv[G] = xptr[G * 128 + jg * 16 + fr];

  float hold = 0.f;

  for (int it = 0; it < SS; ++it) {
    h8v afr[4];
#pragma unroll
    for (int kc = 0; kc < 4; ++kc)
      afr[kc] = *(const h8v*)((const char*)h16 + kc * 64 + qq * 16);

    float xc[3];
#pragma unroll
    for (int G = 0; G < 3; ++G) xc[G] = (float)xv[G];
    if (it < SS - 1) {
      xptr += xstp;
#pragma unroll
      for (int G = 0; G < 3; ++G)
        xv[G] = xptr[G * 128 + jg * 16 + fr];
    }

    f32x4 acc[3];
    acc[0] = (f32x4){xc[0] + bias_[0], 0.f, 0.f, 0.f};
    acc[1] = (f32x4){xc[1] + bias_[1], 0.f, 0.f, 0.f};
    acc[2] = (f32x4){bias_[2], 0.f, 0.f, 0.f};
#pragma unroll
    for (int G = 0; G < 3; ++G)
#pragma unroll
      for (int kc = 0; kc < 4; ++kc)
        acc[G] = __builtin_amdgcn_mfma_f32_16x16x32_f16(
            afr[kc], wB[G][kc], acc[G], 0, 0, 0);

    bar_lds();   // all waves' h-frag reads complete before overwrite

    const float r = sigmoidf_(acc[0][0]);
    const float z = sigmoidf_(acc[1][0]);
    const float n = tanhf_(xc[2] + r * acc[2][0]);
    const float hnew = (1.f - z) * n + z * hold;
    hold = hnew;
    if (qq == 0) {
      const int j = jg * 16 + fr;
      const _Float16 hv = (_Float16)hnew;
      h16[j] = hv;
      hptr[j] = hv;
    }
    hptr += hstp;
    bar_lds();   // h_new visible for next step
  }
}

// ---------------------------------------------------------------------------
// K3: uh16[m][n] = sum_k hcat16[m][k] * Wc[k][n]  (fp16 MFMA, fp16 OUTPUT)
// 128-M tile x full N=160, K=256 staged whole in 64KB swizzled LDS.
// Epilogue: repack acc->fp16 through the (dead) Hs buffer, coalesced stores.
// ---------------------------------------------------------------------------
__global__ __launch_bounds__(256) void k3_uhat(
    const _Float16* __restrict__ hcat16, const _Float16* __restrict__ WcT,
    _Float16* __restrict__ uh16)
{
  __shared__ __align__(16) _Float16 Hs[128 * 256];   // 64KB
  const int tid = threadIdx.x;
  const int m0 = blockIdx.x * 128;
  const int lane = tid & 63, wv = tid >> 6;
  const int fr = lane & 15, qq = lane >> 4;

  const int srow = tid >> 5;   // 0..7
  const int sch  = tid & 31;   // 16B chunk of 512B row
#pragma unroll
  for (int i = 0; i < 16; ++i) {
    const int r = i * 8 + srow;
    const h8v v = *(const h8v*)(hcat16 + (size_t)(m0 + r) * 256 + sch * 8);
    const int off = (r * 512 + sch * 16) ^ ((r & 7) << 4);
    *(h8v*)((char*)Hs + off) = v;
  }
  __syncthreads();

  f32x4 acc[2][10];
#pragma unroll
  for (int mt = 0; mt < 2; ++mt)
#pragma unroll
    for (int nt = 0; nt < 10; ++nt) acc[mt][nt] = (f32x4){0.f, 0.f, 0.f, 0.f};

#pragma unroll
  for (int kc = 0; kc < 8; ++kc) {
    h8v bf_[10];
#pragma unroll
    for (int nt = 0; nt < 10; ++nt)
      bf_[nt] = *(const h8v*)(WcT + (size_t)(nt * 16 + fr) * 256 + kc * 32 + qq * 8);
    h8v af[2];
#pragma unroll
    for (int mt = 0; mt < 2; ++mt) {
      const int rA = wv * 32 + mt * 16 + fr;
      const int off = (rA * 512 + kc * 64 + qq * 16) ^ ((rA & 7) << 4);
      af[mt] = *(const h8v*)((const char*)Hs + off);
    }
#pragma unroll
    for (int mt = 0; mt < 2; ++mt)
#pragma unroll
      for (int nt = 0; nt < 10; ++nt)
        acc[mt][nt] = __builtin_amdgcn_mfma_f32_16x16x32_f16(
            af[mt], bf_[nt], acc[mt][nt], 0, 0, 0);
  }

  __syncthreads();   // Hs frag reads done; reuse as repack buffer (stride 168)
#pragma unroll
  for (int mt = 0; mt < 2; ++mt)
#pragma unroll
    for (int nt = 0; nt < 10; ++nt)
#pragma unroll
      for (int e = 0; e < 4; ++e) {
        const int ml = wv * 32 + mt * 16 + qq * 4 + e;   // 0..127
        Hs[ml * 168 + nt * 16 + fr] = (_Float16)acc[mt][nt][e];
      }
  __syncthreads();
  {
    const int row = tid >> 1;        // 0..127
    const int hf  = tid & 1;         // half of 160 cols
    _Float16* __restrict__ dst = uh16 + (size_t)(m0 + row) * NCDC + hf * 80;
    const _Float16* srcl = &Hs[row * 168 + hf * 80];
#pragma unroll
    for (int i = 0; i < 10; ++i)
      *(h8v*)(dst + i * 8) = *(const h8v*)(srcl + i * 8);
  }
}

// ---------------------------------------------------------------------------
// K4: dynamic routing + final linear. One block per batch element.
// Each thread register-caches its own u-row (160 fp16, filled via coalesced
// 64-row LDS staging) -> b-update is pure register FMA + LDS-broadcast vout.
// v-compute reads global fp16 (coalesced, L2-hot).
// ---------------------------------------------------------------------------
__global__ __launch_bounds__(256) void k4_route(
    const _Float16* __restrict__ uh16, const float* __restrict__ Wl,
    const float* __restrict__ bl, float* __restrict__ outp)
{
  const int b = blockIdx.x;
  const int t = threadIdx.x;
  __shared__ __align__(16) _Float16 stage[64 * 168];   // 21KB
  __shared__ float blog[NC][SS + 1];
  __shared__ float cbuf[NC][SS + 1];
  __shared__ float vout[NC][DC];
  __shared__ float red0[256], red1[256];

  const _Float16* __restrict__ src = uh16 + (size_t)b * SS * NCDC;

  // ---- register-cache u row t (coalesced via LDS staging, 4 chunks) ----
  h4v urow[40];
  for (int chunk = 0; chunk < 4; ++chunk) {
    for (int idx = t; idx < 64 * 20; idx += 256) {
      const int r = idx / 20, c8 = idx % 20;
      const h8v v = *(const h8v*)(src + (size_t)(chunk * 64 + r) * NCDC + c8 * 8);
      _Float16* d = &stage[r * 168 + c8 * 8];
      *(h4v*)(d)     = (h4v){v[0], v[1], v[2], v[3]};
      *(h4v*)(d + 4) = (h4v){v[4], v[5], v[6], v[7]};
    }
    __syncthreads();
    if ((t >> 6) == chunk) {
      const int r = t & 63;
#pragma unroll
      for (int q = 0; q < 40; ++q)
        urow[q] = *(const h4v*)(&stage[r * 168 + q * 4]);
    }
    __syncthreads();
  }

#pragma unroll
  for (int i = 0; i < NC; ++i) blog[i][t] = 0.f;
  __syncthreads();

  const int ci = t >> 4, ck = t & 15;
  float myval = 0.f;

  for (int it = 0; it < 5; ++it) {
    float m = blog[0][t];
#pragma unroll
    for (int i = 1; i < NC; ++i) m = fmaxf(m, blog[i][t]);
    float e[NC];
    float sum = 0.f;
#pragma unroll
    for (int i = 0; i < NC; ++i) { e[i] = __expf(blog[i][t] - m); sum += e[i]; }
    const float inv = __builtin_amdgcn_rcpf(sum);
#pragma unroll
    for (int i = 0; i < NC; ++i) cbuf[i][t] = e[i] * inv;
    __syncthreads();

    if (t < NCDC) {
      float acc0 = 0.f, acc1 = 0.f;
#pragma unroll 8
      for (int jj = 0; jj < SS; jj += 2) {
        acc0 += cbuf[ci][jj] * (float)src[(size_t)jj * NCDC + t];
        acc1 += cbuf[ci][jj + 1] * (float)src[(size_t)(jj + 1) * NCDC + t];
      }
      const float acc = acc0 + acc1;
      float ss = acc * acc;
      ss += __shfl_xor(ss, 1);
      ss += __shfl_xor(ss, 2);
      ss += __shfl_xor(ss, 4);
      ss += __shfl_xor(ss, 8);
      myval = acc * __builtin_amdgcn_rsqf(ss + CAP_EPS);
      vout[ci][ck] = myval;
    }
    __syncthreads();

    if (it < 4) {
#pragma unroll
      for (int i = 0; i < NC; ++i) {
        float dot = 0.f;
#pragma unroll
        for (int q = 0; q < 4; ++q) {
          const h4v u4 = urow[i * 4 + q];
          dot += (float)u4[0] * vout[i][q * 4 + 0]
               + (float)u4[1] * vout[i][q * 4 + 1]
               + (float)u4[2] * vout[i][q * 4 + 2]
               + (float)u4[3] * vout[i][q * 4 + 3];
        }
        blog[i][t] += dot;
      }
      __syncthreads();
    }
  }

  float p0 = 0.f, p1 = 0.f;
  if (t < NCDC) { p0 = myval * Wl[2 * t]; p1 = myval * Wl[2 * t + 1]; }
  red0[t] = p0; red1[t] = p1;
  __syncthreads();
  for (int off = 128; off >= 1; off >>= 1) {
    if (t < off) { red0[t] += red0[t + off]; red1[t] += red1[t + off]; }
    __syncthreads();
  }
  if (t == 0) {
    outp[2 * b + 0] = red0[0] + bl[0];
    outp[2 * b + 1] = red1[0] + bl[1];
  }
}

extern "C" void kernel_launch(void* const* d_in, const int* in_sizes, int n_in,
                              void* d_out, int out_size, void* d_ws, size_t ws_size,
                              hipStream_t stream) {
  (void)in_sizes; (void)n_in; (void)out_size; (void)ws_size;
  const int*   x    = (const int*)  d_in[0];
  const float* emb  = (const float*)d_in[1];
  const float* wif  = (const float*)d_in[2];
  const float* whf  = (const float*)d_in[3];
  const float* bif  = (const float*)d_in[4];
  const float* bhf  = (const float*)d_in[5];
  const float* wib  = (const float*)d_in[6];
  const float* whb  = (const float*)d_in[7];
  const float* bib  = (const float*)d_in[8];
  const float* bhb  = (const float*)d_in[9];
  const float* Wc   = (const float*)d_in[10];
  const float* Wl   = (const float*)d_in[11];
  const float* bl   = (const float*)d_in[12];
  float* out = (float*)d_out;

  char* base = (char*)d_ws;
  _Float16* xp16   = (_Float16*)base;                       //  50.33 MB
  _Float16* hcat16 = (_Float16*)(base + 50331648);          //  16.78 MB
  _Float16* uh16   = (_Float16*)(base + 67108864);          //  10.49 MB
  _Float16* A16    = (_Float16*)(base + 88080384);          //  20.97 MB
  _Float16* Bw16   = (_Float16*)(base + 109051904);         //   0.49 MB
  _Float16* WcT    = (_Float16*)(base + 109543424);         //   0.08 MB

  hipLaunchKernelGGL(k0_prep, dim3(33696), dim3(64), 0, stream,
                     x, emb, wif, wib, Wc, A16, Bw16, WcT);
  hipLaunchKernelGGL(k1_xproj, dim3(256, 6), dim3(256), 0, stream,
                     A16, Bw16, bif, bib, xp16);
  hipLaunchKernelGGL(k2_gru, dim3(256), dim3(512), 0, stream,
                     xp16, whf, whb, bhf, bhb, hcat16);
  hipLaunchKernelGGL(k3_uhat, dim3(256), dim3(256), 0, stream,
                     hcat16, WcT, uh16);
  hipLaunchKernelGGL(k4_route, dim3(128), dim3(256), 0, stream,
                     uh16, Wl, bl, out);
}

// Round 12
// 217.637 us; speedup vs baseline: 1.7648x; 1.0003x over previous
//
#include <hip/hip_runtime.h>
#include <cmath>

#define DW 300
#define HH 128
#define G3 384
#define GN 768
#define SS 256
#define NB 128
#define NC 10
#define DC 16
#define NCDC 160
#define CAP_EPS 1e-7f
#define KP 320

typedef _Float16 h8v __attribute__((ext_vector_type(8)));
typedef _Float16 h4v __attribute__((ext_vector_type(4)));
typedef float f32x4 __attribute__((ext_vector_type(4)));

__device__ __forceinline__ float rcp_(float x) { return __builtin_amdgcn_rcpf(x); }
__device__ __forceinline__ float sigmoidf_(float x) {
  return rcp_(1.0f + __expf(-x));
}
__device__ __forceinline__ float tanhf_(float x) {
  return 1.0f - 2.0f * rcp_(__expf(2.0f * x) + 1.0f);
}
// LDS-only barrier: don't drain vmcnt, so global loads/stores stay in flight.
__device__ __forceinline__ void bar_lds() {
  asm volatile("s_waitcnt lgkmcnt(0)\n\ts_barrier" ::: "memory");
}

// ---------------------------------------------------------------------------
// K0: gather emb rows -> A16[32768][320] fp16 (K padded 300->320 with zeros),
// convert w_ih (f+b) -> Bw16[768][320], transpose W_cap -> WcT[160][256].
// ---------------------------------------------------------------------------
__global__ __launch_bounds__(64) void k0_prep(
    const int* __restrict__ x, const float* __restrict__ emb,
    const float* __restrict__ wif, const float* __restrict__ wib,
    const float* __restrict__ Wc,
    _Float16* __restrict__ A16, _Float16* __restrict__ Bw16,
    _Float16* __restrict__ WcT)
{
  const int row = blockIdx.x;
  const int t = threadIdx.x;
  if (row < 33536) {
    const float* __restrict__ src;
    _Float16* __restrict__ dst;
    if (row < 32768) {
      src = emb + (size_t)x[(row & 127) * SS + (row >> 7)] * DW;
      dst = A16 + (size_t)row * KP;
    } else {
      const int n = row - 32768;
      src = (n < G3) ? (wif + (size_t)n * DW) : (wib + (size_t)(n - G3) * DW);
      dst = Bw16 + (size_t)n * KP;
    }
#pragma unroll
    for (int p = 0; p < 2; ++p) {
      const int idx = p * 64 + t;
      if (idx < 75) {
        const float4 v = *(const float4*)(src + idx * 4);
        h4v o = {(_Float16)v.x, (_Float16)v.y, (_Float16)v.z, (_Float16)v.w};
        *(h4v*)(dst + idx * 4) = o;
      }
    }
    if (t < 5) {
      h4v z = {(_Float16)0.f, (_Float16)0.f, (_Float16)0.f, (_Float16)0.f};
      *(h4v*)(dst + 300 + t * 4) = z;
    }
  } else {
    const int n = row - 33536;   // 0..159
    _Float16* __restrict__ dst = WcT + (size_t)n * 256;
#pragma unroll
    for (int p = 0; p < 4; ++p) {
      const int k = p * 64 + t;
      dst[k] = (_Float16)Wc[(size_t)k * NCDC + n];
    }
  }
}

// ---------------------------------------------------------------------------
// K1: fp16 MFMA GEMM for x-projection.  DOUBLE-BUFFERED LDS, 1 barrier/K-tile.
// m-tile (128) == one timestep s, all 128 batches; n-tile (128) == one (dir,G).
// Per K-tile kt: MFMA from buf[kt&1]; ds_write prefetched tile kt+1 into
// buf[(kt+1)&1]; global-load tile kt+2 into regs; ONE bar_lds.
// W-after-R proof: buf[(kt+1)&1] was last read at iter kt-1; those reads
// completed before barrier(kt-1) (lgkmcnt(0) precedes it); writes at kt occur
// after this wave passed barrier(kt-1).  R-after-W: barrier(kt) precedes the
// kt+1 reads and follows all ds_writes (lgkmcnt(0)).
// Epilogue: bias + fp16 repack via arena-aliased Ls (stride 136 = 16B-aligned
// rows), coalesced h8v stores to xp16[dir][b][s][G*128+j].
// ---------------------------------------------------------------------------
__global__ __launch_bounds__(256) void k1_xproj(
    const _Float16* __restrict__ A16, const _Float16* __restrict__ Bw16,
    const float* __restrict__ bf, const float* __restrict__ bb,
    _Float16* __restrict__ xp16)
{
  __shared__ __align__(16) char arena[65536];   // A0|B0|A1|B1 (16KB each)
  const int tid = threadIdx.x;
  const int s_idx = blockIdx.x;          // timestep
  const int n0 = blockIdx.y * 128;       // (dir, G)
  const int m0 = s_idx * 128;
  const int dir = (n0 >= G3) ? 1 : 0;
  const int G = (n0 >> 7) - dir * 3;

  const int lane = tid & 63;
  const int wv = tid >> 6, wm = wv >> 1, wn = wv & 1;
  const int fr = lane & 15, kc4 = lane >> 4;

  const int srow = tid >> 3;   // 0..31 (+i*32)
  const int sch  = tid & 7;    // 16B chunk within 128B row

  f32x4 acc[4][4];
#pragma unroll
  for (int i = 0; i < 4; ++i)
#pragma unroll
    for (int j = 0; j < 4; ++j) acc[i][j] = (f32x4){0.f, 0.f, 0.f, 0.f};

  h8v ra[4], rb[4];
  // ---- prologue: tile0 -> buf0; prefetch tile1 -> regs ----
#pragma unroll
  for (int i = 0; i < 4; ++i) {
    const int r = i * 32 + srow;
    ra[i] = *(const h8v*)(A16 + (size_t)(m0 + r) * KP + sch * 8);
    rb[i] = *(const h8v*)(Bw16 + (size_t)(n0 + r) * KP + sch * 8);
  }
#pragma unroll
  for (int i = 0; i < 4; ++i) {
    const int r = i * 32 + srow;
    const int off = (r * 128 + sch * 16) ^ ((r & 7) << 4);
    *(h8v*)(arena + off) = ra[i];
    *(h8v*)(arena + 16384 + off) = rb[i];
  }
#pragma unroll
  for (int i = 0; i < 4; ++i) {
    const int r = i * 32 + srow;
    ra[i] = *(const h8v*)(A16 + (size_t)(m0 + r) * KP + 64 + sch * 8);
    rb[i] = *(const h8v*)(Bw16 + (size_t)(n0 + r) * KP + 64 + sch * 8);
  }
  bar_lds();                            // buf0 visible

#pragma unroll
  for (int kt = 0; kt < 5; ++kt) {
    const char* __restrict__ Ab = arena + ((kt & 1) ? 32768 : 0);
    const char* __restrict__ Bb = Ab + 16384;

    h8v af[4][2], bfv[4][2];
#pragma unroll
    for (int mf = 0; mf < 4; ++mf) {
      const int rA = wm * 64 + mf * 16 + fr;
#pragma unroll
      for (int ks = 0; ks < 2; ++ks) {
        const int off = (rA * 128 + ks * 64 + kc4 * 16) ^ ((rA & 7) << 4);
        af[mf][ks] = *(const h8v*)(Ab + off);
      }
    }
#pragma unroll
    for (int nf = 0; nf < 4; ++nf) {
      const int rB = wn * 64 + nf * 16 + fr;
#pragma unroll
      for (int ks = 0; ks < 2; ++ks) {
        const int off = (rB * 128 + ks * 64 + kc4 * 16) ^ ((rB & 7) << 4);
        bfv[nf][ks] = *(const h8v*)(Bb + off);
      }
    }
#pragma unroll
    for (int ks = 0; ks < 2; ++ks)
#pragma unroll
      for (int mf = 0; mf < 4; ++mf)
#pragma unroll
        for (int nf = 0; nf < 4; ++nf)
          acc[mf][nf] = __builtin_amdgcn_mfma_f32_16x16x32_f16(
              af[mf][ks], bfv[nf][ks], acc[mf][nf], 0, 0, 0);

    if (kt < 4) {
      // ds_write prefetched tile kt+1 into the other buffer
      char* __restrict__ Aw = arena + (((kt + 1) & 1) ? 32768 : 0);
#pragma unroll
      for (int i = 0; i < 4; ++i) {
        const int r = i * 32 + srow;
        const int off = (r * 128 + sch * 16) ^ ((r & 7) << 4);
        *(h8v*)(Aw + off) = ra[i];
        *(h8v*)(Aw + 16384 + off) = rb[i];
      }
      if (kt < 3) {
        const int kb = (kt + 2) * 64;
#pragma unroll
        for (int i = 0; i < 4; ++i) {
          const int r = i * 32 + srow;
          ra[i] = *(const h8v*)(A16 + (size_t)(m0 + r) * KP + kb + sch * 8);
          rb[i] = *(const h8v*)(Bw16 + (size_t)(n0 + r) * KP + kb + sch * 8);
        }
      }
    }
    bar_lds();   // tile kt+1 visible; guards W-after-R for next iter
  }

  // ---- epilogue: bias + fp16 repack in arena-aliased Ls, coalesced store ----
  const float* __restrict__ bsrc = (n0 < G3) ? (bf + n0) : (bb + (n0 - G3));
  float bval[4];
#pragma unroll
  for (int nf = 0; nf < 4; ++nf) bval[nf] = bsrc[wn * 64 + nf * 16 + fr];

  _Float16* __restrict__ Ls = (_Float16*)arena;   // [128][136], 34.8KB
#pragma unroll
  for (int mf = 0; mf < 4; ++mf)
#pragma unroll
    for (int e = 0; e < 4; ++e) {
      const int r = wm * 64 + mf * 16 + kc4 * 4 + e;   // batch b
#pragma unroll
      for (int nf = 0; nf < 4; ++nf) {
        const int c = wn * 64 + nf * 16 + fr;          // j within gate
        Ls[r * 136 + c] = (_Float16)(acc[mf][nf][e] + bval[nf]);
      }
    }
  bar_lds();

  // 256 threads: unit = (row b, half): 128B contiguous per unit
  {
    const int r = tid >> 1;
    const int hf = tid & 1;
    _Float16* __restrict__ dst =
        xp16 + ((size_t)(dir * NB + r) * SS + s_idx) * G3 + G * 128 + hf * 64;
    const _Float16* srcl = &Ls[r * 136 + hf * 64];
#pragma unroll
    for (int i = 0; i < 8; ++i)
      *(h8v*)(dst + i * 8) = *(const h8v*)(srcl + i * 8);
  }
}

// ---------------------------------------------------------------------------
// K2: GRU recurrence via MFMA. 256 blocks = (dir, b), full chip; 8 waves
// (512 thr, 2 waves/SIMD). Wave jg owns ONE j-tile (16 units), all 3 gates.
// PROVEN two-barrier protocol. FROZEN from round 10 (125 us).
// ---------------------------------------------------------------------------
__global__ __launch_bounds__(512) void k2_gru(
    const _Float16* __restrict__ xp16,
    const float* __restrict__ whf, const float* __restrict__ whb,
    const float* __restrict__ bhf, const float* __restrict__ bhb,
    _Float16* __restrict__ hcat16)
{
  const int blk = blockIdx.x;      // 0..255
  const int dir = blk >> 7;
  const int b   = blk & 127;
  const int tid = threadIdx.x;
  const int jg  = tid >> 6;        // wave = j-tile owner, 0..7
  const int lane = tid & 63;
  const int fr = lane & 15;
  const int qq = lane >> 4;

  const float* __restrict__ wh = dir ? whb : whf;
  const float* __restrict__ bh = dir ? bhb : bhf;

  h8v wB[3][4];
  float bias_[3];
#pragma unroll
  for (int G = 0; G < 3; ++G) {
    const int row = G * HH + jg * 16 + fr;
    const float* __restrict__ p = wh + (size_t)row * HH;
#pragma unroll
    for (int kc = 0; kc < 4; ++kc) {
      const float* q = p + kc * 32 + qq * 8;
      const float4 u0 = *(const float4*)(q);
      const float4 u1 = *(const float4*)(q + 4);
      wB[G][kc] = (h8v){(_Float16)u0.x, (_Float16)u0.y, (_Float16)u0.z,
                        (_Float16)u0.w, (_Float16)u1.x, (_Float16)u1.y,
                        (_Float16)u1.z, (_Float16)u1.w};
    }
    bias_[G] = bh[G * HH + jg * 16 + fr];
  }

  __shared__ __align__(16) _Float16 h16[HH];   // 256 B
  if (tid < 16) *(h8v*)(h16 + tid * 8) = (h8v){0, 0, 0, 0, 0, 0, 0, 0};
  __syncthreads();

  const int stp = dir ? -1 : 1;
  int s = dir ? (SS - 1) : 0;
  const ptrdiff_t xstp = (ptrdiff_t)stp * G3;
  const ptrdiff_t hstp = (ptrdiff_t)stp * 256;
  const _Float16* __restrict__ xptr =
      xp16 + (size_t)(dir * NB + b) * SS * G3 + (size_t)s * G3;
  _Float16* __restrict__ hptr =
      hcat16 + ((size_t)b * SS + s) * 256 + dir * HH;

  _Float16 xv[3];
#pragma unroll
  for (int G = 0; G < 3; ++G)
    xv[G] = xptr[G * 128 + jg * 16 + fr];

  float hold = 0.f;

  for (int it = 0; it < SS; ++it) {
    h8v afr[4];
#pragma unroll
    for (int kc = 0; kc < 4; ++kc)
      afr[kc] = *(const h8v*)((const char*)h16 + kc * 64 + qq * 16);

    float xc[3];
#pragma unroll
    for (int G = 0; G < 3; ++G) xc[G] = (float)xv[G];
    if (it < SS - 1) {
      xptr += xstp;
#pragma unroll
      for (int G = 0; G < 3; ++G)
        xv[G] = xptr[G * 128 + jg * 16 + fr];
    }

    f32x4 acc[3];
    acc[0] = (f32x4){xc[0] + bias_[0], 0.f, 0.f, 0.f};
    acc[1] = (f32x4){xc[1] + bias_[1], 0.f, 0.f, 0.f};
    acc[2] = (f32x4){bias_[2], 0.f, 0.f, 0.f};
#pragma unroll
    for (int G = 0; G < 3; ++G)
#pragma unroll
      for (int kc = 0; kc < 4; ++kc)
        acc[G] = __builtin_amdgcn_mfma_f32_16x16x32_f16(
            afr[kc], wB[G][kc], acc[G], 0, 0, 0);

    bar_lds();   // all waves' h-frag reads complete before overwrite

    const float r = sigmoidf_(acc[0][0]);
    const float z = sigmoidf_(acc[1][0]);
    const float n = tanhf_(xc[2] + r * acc[2][0]);
    const float hnew = (1.f - z) * n + z * hold;
    hold = hnew;
    if (qq == 0) {
      const int j = jg * 16 + fr;
      const _Float16 hv = (_Float16)hnew;
      h16[j] = hv;
      hptr[j] = hv;
    }
    hptr += hstp;
    bar_lds();   // h_new visible for next step
  }
}

// ---------------------------------------------------------------------------
// K3: uh16[m][n] = sum_k hcat16[m][k] * Wc[k][n]  (fp16 MFMA, fp16 OUTPUT)
// 128-M tile x full N=160, K=256 staged whole in 64KB swizzled LDS.
// ---------------------------------------------------------------------------
__global__ __launch_bounds__(256) void k3_uhat(
    const _Float16* __restrict__ hcat16, const _Float16* __restrict__ WcT,
    _Float16* __restrict__ uh16)
{
  __shared__ __align__(16) _Float16 Hs[128 * 256];   // 64KB
  const int tid = threadIdx.x;
  const int m0 = blockIdx.x * 128;
  const int lane = tid & 63, wv = tid >> 6;
  const int fr = lane & 15, qq = lane >> 4;

  const int srow = tid >> 5;   // 0..7
  const int sch  = tid & 31;   // 16B chunk of 512B row
#pragma unroll
  for (int i = 0; i < 16; ++i) {
    const int r = i * 8 + srow;
    const h8v v = *(const h8v*)(hcat16 + (size_t)(m0 + r) * 256 + sch * 8);
    const int off = (r * 512 + sch * 16) ^ ((r & 7) << 4);
    *(h8v*)((char*)Hs + off) = v;
  }
  __syncthreads();

  f32x4 acc[2][10];
#pragma unroll
  for (int mt = 0; mt < 2; ++mt)
#pragma unroll
    for (int nt = 0; nt < 10; ++nt) acc[mt][nt] = (f32x4){0.f, 0.f, 0.f, 0.f};

#pragma unroll
  for (int kc = 0; kc < 8; ++kc) {
    h8v bf_[10];
#pragma unroll
    for (int nt = 0; nt < 10; ++nt)
      bf_[nt] = *(const h8v*)(WcT + (size_t)(nt * 16 + fr) * 256 + kc * 32 + qq * 8);
    h8v af[2];
#pragma unroll
    for (int mt = 0; mt < 2; ++mt) {
      const int rA = wv * 32 + mt * 16 + fr;
      const int off = (rA * 512 + kc * 64 + qq * 16) ^ ((rA & 7) << 4);
      af[mt] = *(const h8v*)((const char*)Hs + off);
    }
#pragma unroll
    for (int mt = 0; mt < 2; ++mt)
#pragma unroll
      for (int nt = 0; nt < 10; ++nt)
        acc[mt][nt] = __builtin_amdgcn_mfma_f32_16x16x32_f16(
            af[mt], bf_[nt], acc[mt][nt], 0, 0, 0);
  }

  __syncthreads();   // Hs frag reads done; reuse as repack buffer (stride 168)
#pragma unroll
  for (int mt = 0; mt < 2; ++mt)
#pragma unroll
    for (int nt = 0; nt < 10; ++nt)
#pragma unroll
      for (int e = 0; e < 4; ++e) {
        const int ml = wv * 32 + mt * 16 + qq * 4 + e;   // 0..127
        Hs[ml * 168 + nt * 16 + fr] = (_Float16)acc[mt][nt][e];
      }
  __syncthreads();
  {
    const int row = tid >> 1;        // 0..127
    const int hf  = tid & 1;         // half of 160 cols
    _Float16* __restrict__ dst = uh16 + (size_t)(m0 + row) * NCDC + hf * 80;
    const _Float16* srcl = &Hs[row * 168 + hf * 80];
#pragma unroll
    for (int i = 0; i < 10; ++i)
      *(h8v*)(dst + i * 8) = *(const h8v*)(srcl + i * 8);
  }
}

// ---------------------------------------------------------------------------
// K4: dynamic routing + final linear. One block per batch element.
// Register-cached u-rows; LDS-broadcast vout; coalesced v-compute reads.
// ---------------------------------------------------------------------------
__global__ __launch_bounds__(256) void k4_route(
    const _Float16* __restrict__ uh16, const float* __restrict__ Wl,
    const float* __restrict__ bl, float* __restrict__ outp)
{
  const int b = blockIdx.x;
  const int t = threadIdx.x;
  __shared__ __align__(16) _Float16 stage[64 * 168];   // 21KB
  __shared__ float blog[NC][SS + 1];
  __shared__ float cbuf[NC][SS + 1];
  __shared__ float vout[NC][DC];
  __shared__ float red0[256], red1[256];

  const _Float16* __restrict__ src = uh16 + (size_t)b * SS * NCDC;

  // ---- register-cache u row t (coalesced via LDS staging, 4 chunks) ----
  h4v urow[40];
  for (int chunk = 0; chunk < 4; ++chunk) {
    for (int idx = t; idx < 64 * 20; idx += 256) {
      const int r = idx / 20, c8 = idx % 20;
      const h8v v = *(const h8v*)(src + (size_t)(chunk * 64 + r) * NCDC + c8 * 8);
      _Float16* d = &stage[r * 168 + c8 * 8];
      *(h4v*)(d)     = (h4v){v[0], v[1], v[2], v[3]};
      *(h4v*)(d + 4) = (h4v){v[4], v[5], v[6], v[7]};
    }
    __syncthreads();
    if ((t >> 6) == chunk) {
      const int r = t & 63;
#pragma unroll
      for (int q = 0; q < 40; ++q)
        urow[q] = *(const h4v*)(&stage[r * 168 + q * 4]);
    }
    __syncthreads();
  }

#pragma unroll
  for (int i = 0; i < NC; ++i) blog[i][t] = 0.f;
  __syncthreads();

  const int ci = t >> 4, ck = t & 15;
  float myval = 0.f;

  for (int it = 0; it < 5; ++it) {
    float m = blog[0][t];
#pragma unroll
    for (int i = 1; i < NC; ++i) m = fmaxf(m, blog[i][t]);
    float e[NC];
    float sum = 0.f;
#pragma unroll
    for (int i = 0; i < NC; ++i) { e[i] = __expf(blog[i][t] - m); sum += e[i]; }
    const float inv = __builtin_amdgcn_rcpf(sum);
#pragma unroll
    for (int i = 0; i < NC; ++i) cbuf[i][t] = e[i] * inv;
    __syncthreads();

    if (t < NCDC) {
      float acc0 = 0.f, acc1 = 0.f;
#pragma unroll 8
      for (int jj = 0; jj < SS; jj += 2) {
        acc0 += cbuf[ci][jj] * (float)src[(size_t)jj * NCDC + t];
        acc1 += cbuf[ci][jj + 1] * (float)src[(size_t)(jj + 1) * NCDC + t];
      }
      const float acc = acc0 + acc1;
      float ss = acc * acc;
      ss += __shfl_xor(ss, 1);
      ss += __shfl_xor(ss, 2);
      ss += __shfl_xor(ss, 4);
      ss += __shfl_xor(ss, 8);
      myval = acc * __builtin_amdgcn_rsqf(ss + CAP_EPS);
      vout[ci][ck] = myval;
    }
    __syncthreads();

    if (it < 4) {
#pragma unroll
      for (int i = 0; i < NC; ++i) {
        float dot = 0.f;
#pragma unroll
        for (int q = 0; q < 4; ++q) {
          const h4v u4 = urow[i * 4 + q];
          dot += (float)u4[0] * vout[i][q * 4 + 0]
               + (float)u4[1] * vout[i][q * 4 + 1]
               + (float)u4[2] * vout[i][q * 4 + 2]
               + (float)u4[3] * vout[i][q * 4 + 3];
        }
        blog[i][t] += dot;
      }
      __syncthreads();
    }
  }

  float p0 = 0.f, p1 = 0.f;
  if (t < NCDC) { p0 = myval * Wl[2 * t]; p1 = myval * Wl[2 * t + 1]; }
  red0[t] = p0; red1[t] = p1;
  __syncthreads();
  for (int off = 128; off >= 1; off >>= 1) {
    if (t < off) { red0[t] += red0[t + off]; red1[t] += red1[t + off]; }
    __syncthreads();
  }
  if (t == 0) {
    outp[2 * b + 0] = red0[0] + bl[0];
    outp[2 * b + 1] = red1[0] + bl[1];
  }
}

extern "C" void kernel_launch(void* const* d_in, const int* in_sizes, int n_in,
                              void* d_out, int out_size, void* d_ws, size_t ws_size,
                              hipStream_t stream) {
  (void)in_sizes; (void)n_in; (void)out_size; (void)ws_size;
  const int*   x    = (const int*)  d_in[0];
  const float* emb  = (const float*)d_in[1];
  const float* wif  = (const float*)d_in[2];
  const float* whf  = (const float*)d_in[3];
  const float* bif  = (const float*)d_in[4];
  const float* bhf  = (const float*)d_in[5];
  const float* wib  = (const float*)d_in[6];
  const float* whb  = (const float*)d_in[7];
  const float* bib  = (const float*)d_in[8];
  const float* bhb  = (const float*)d_in[9];
  const float* Wc   = (const float*)d_in[10];
  const float* Wl   = (const float*)d_in[11];
  const float* bl   = (const float*)d_in[12];
  float* out = (float*)d_out;

  char* base = (char*)d_ws;
  _Float16* xp16   = (_Float16*)base;                       //  50.33 MB
  _Float16* hcat16 = (_Float16*)(base + 50331648);          //  16.78 MB
  _Float16* uh16   = (_Float16*)(base + 67108864);          //  10.49 MB
  _Float16* A16    = (_Float16*)(base + 88080384);          //  20.97 MB
  _Float16* Bw16   = (_Float16*)(base + 109051904);         //   0.49 MB
  _Float16* WcT    = (_Float16*)(base + 109543424);         //   0.08 MB

  hipLaunchKernelGGL(k0_prep, dim3(33696), dim3(64), 0, stream,
                     x, emb, wif, wib, Wc, A16, Bw16, WcT);
  hipLaunchKernelGGL(k1_xproj, dim3(256, 6), dim3(256), 0, stream,
                     A16, Bw16, bif, bib, xp16);
  hipLaunchKernelGGL(k2_gru, dim3(256), dim3(512), 0, stream,
                     xp16, whf, whb, bhf, bhb, hcat16);
  hipLaunchKernelGGL(k3_uhat, dim3(256), dim3(256), 0, stream,
                     hcat16, WcT, uh16);
  hipLaunchKernelGGL(k4_route, dim3(128), dim3(256), 0, stream,
                     uh16, Wl, bl, out);
}